// Round 2
// baseline (842.443 us; speedup 1.0000x reference)
//
#include <hip/hip_runtime.h>

#define AS1 __attribute__((address_space(1)))
#define AS3 __attribute__((address_space(3)))

typedef __attribute__((ext_vector_type(8))) short short8;
typedef __attribute__((ext_vector_type(4))) float f32x4;
typedef unsigned int u32;
typedef unsigned short u16;

static constexpr int NN = 20000;
static constexpr int NE = 320000;
static constexpr int INC = 2000;
static constexpr int KX = 2048;
static constexpr int HID = 512;
static constexpr int OUTC = 256;
static constexpr int QA = 100;
static constexpr int KQ = 128;
static constexpr long OUTSZ = (long)NN * OUTC;
static constexpr int NB79 = (NN + 255) / 256;   // 79

__device__ __forceinline__ u16 f2bf(float f) {
  u32 u = __float_as_uint(f);
  u = (u + 0x7FFFu + ((u >> 16) & 1u)) >> 16;   // RNE
  return (u16)u;
}
__device__ __forceinline__ void ld_bf16x8(const u16* p, float* f) {
  uint4 r = *(const uint4*)p;
  f[0] = __uint_as_float(r.x << 16); f[1] = __uint_as_float(r.x & 0xFFFF0000u);
  f[2] = __uint_as_float(r.y << 16); f[3] = __uint_as_float(r.y & 0xFFFF0000u);
  f[4] = __uint_as_float(r.z << 16); f[5] = __uint_as_float(r.z & 0xFFFF0000u);
  f[6] = __uint_as_float(r.w << 16); f[7] = __uint_as_float(r.w & 0xFFFF0000u);
}
__device__ __forceinline__ void ld_bf16x4(const u16* p, float* f) {
  uint2 r = *(const uint2*)p;
  f[0] = __uint_as_float(r.x << 16); f[1] = __uint_as_float(r.x & 0xFFFF0000u);
  f[2] = __uint_as_float(r.y << 16); f[3] = __uint_as_float(r.y & 0xFFFF0000u);
}

// ---------------- fused prep kernel ----------------
// R0 [0,20000): x_RNA row cast->Xb ; R1 [20000,21250): x_ADT cast (16 rows/blk)
// R2 [21250,21522): 5 small-weight transposes ; R3 [21522,22034): WcT LDS transpose
// R4 [22034,22803): Wcat compose + bias2 ; R5 [22803,23038): CSR state init
struct Prep {
  const float *xR, *xA;
  const float *W1, *W2;                     // W_rna1, W_rna2
  const float *Ws0, *Ws1, *Ws2, *Ws3, *Ws4; // W_sim, W_dist, W_f1, W_f2, W_p3
  u16 *Wo0, *Wo1, *Wo2, *Wo3, *Wo4;
  const float *bf1, *bf2;
  u16 *Xb, *ADTb, *WcT, *WcatT;
  float *bias2;
  float *deg; int *cnt; int *cur;
};

__global__ __launch_bounds__(256) void k_prep(Prep P) {
  int b = blockIdx.x, t = threadIdx.x;
  if (b < 20000) {                       // ---- R0: x_RNA row cast
    int c8 = t << 3;
    u16 v[8];
    if (c8 + 8 <= INC) {
      const float4* p = (const float4*)(P.xR + (long)b * INC + c8);
      float4 a = p[0], c = p[1];
      v[0] = f2bf(a.x); v[1] = f2bf(a.y); v[2] = f2bf(a.z); v[3] = f2bf(a.w);
      v[4] = f2bf(c.x); v[5] = f2bf(c.y); v[6] = f2bf(c.z); v[7] = f2bf(c.w);
    } else {
#pragma unroll
      for (int j = 0; j < 8; j++) {
        int c = c8 + j;
        v[j] = (c < INC) ? f2bf(P.xR[(long)b * INC + c]) : (u16)0;
      }
    }
    *(uint4*)(P.Xb + (long)b * KX + c8) = *(const uint4*)v;
    return;
  }
  if (b < 21250) {                       // ---- R1: x_ADT cast, 16 rows/block
    int row = (b - 20000) * 16 + (t >> 4);
    int c8 = (t & 15) << 3;
    u16 v[8];
#pragma unroll
    for (int j = 0; j < 8; j++) {
      int c = c8 + j;
      v[j] = (c < QA) ? f2bf(P.xA[(long)row * QA + c]) : (u16)0;
    }
    *(uint4*)(P.ADTb + (long)row * KQ + c8) = *(const uint4*)v;
    return;
  }
  if (b < 21522) {                       // ---- R2: wT5
    int slot = (b - 21250) * 256 + t;
    const float* W; u16* o; int Kin, Kpad, within;
    if (slot < 65536) {
      int j = slot >> 14; within = slot & 16383;
      W = (j == 0) ? P.Ws0 : (j == 1) ? P.Ws1 : (j == 2) ? P.Ws2 : P.Ws3;
      o = (j == 0) ? P.Wo0 : (j == 1) ? P.Wo1 : (j == 2) ? P.Wo2 : P.Wo3;
      Kin = HID; Kpad = HID;
    } else {
      within = slot - 65536; W = P.Ws4; o = P.Wo4; Kin = QA; Kpad = KQ;
    }
    int kg = Kpad >> 3;
    int n = within / kg, k8 = (within % kg) << 3;
    u16 v[8];
#pragma unroll
    for (int j = 0; j < 8; j++) {
      int k = k8 + j;
      v[j] = (k < Kin) ? f2bf(W[(long)k * OUTC + n]) : (u16)0;
    }
    *(uint4*)(o + (long)n * Kpad + k8) = *(const uint4*)v;
    return;
  }
  if (b < 22034) {                       // ---- R3: WcT transpose
    __shared__ float tile[64][65];
    int bb = b - 21522;
    int kb = (bb & 31) * 64, nb = (bb >> 5) * 64;
    const float* W = (nb < HID) ? P.W1 : P.W2;
    int nb2 = nb & (HID - 1);
#pragma unroll
    for (int p = 0; p < 4; p++) {
      int idx = p * 256 + t;
      int r = idx >> 4, c4 = (idx & 15) << 2;
      int k = kb + r;
      float4 v = {0.f, 0.f, 0.f, 0.f};
      if (k < INC) v = *(const float4*)(W + (long)k * HID + nb2 + c4);
      tile[r][c4] = v.x; tile[r][c4 + 1] = v.y; tile[r][c4 + 2] = v.z; tile[r][c4 + 3] = v.w;
    }
    __syncthreads();
#pragma unroll
    for (int p = 0; p < 2; p++) {
      int idx = p * 256 + t;
      int n = idx >> 3, kg = (idx & 7) << 3;
      u16 v[8];
#pragma unroll
      for (int j = 0; j < 8; j++) v[j] = f2bf(tile[kg + j][n]);
      *(uint4*)(P.WcT + (long)(nb + n) * KX + kb + kg) = *(const uint4*)v;
    }
    return;
  }
  if (b < 22803) {                       // ---- R4: Wcat compose
    int k = b - 22034;                   // 0..768 (768 == bias block)
    int n = t;
    if (k < 512) {
      float s = 0.f;
      for (int j = 0; j < 256; j++) s += P.Ws2[k * OUTC + j] * P.Ws3[j * OUTC + n];
      P.WcatT[(long)n * 768 + k] = f2bf(s);
    } else if (k < 768) {
      P.WcatT[(long)n * 768 + k] = f2bf(P.Ws3[(256 + k - 512) * OUTC + n]);
    } else {
      float s = P.bf2[n];
      for (int j = 0; j < 256; j++) s += P.bf1[j] * P.Ws3[j * OUTC + n];
      P.bias2[n] = s;
    }
    return;
  }
  {                                      // ---- R5: CSR init
    int i = (b - 22803) * 256 + t;
    if (i < 3 * NN) { P.deg[i] = 1.0f; P.cnt[i] = 0; P.cur[i] = 0; }
  }
}

// ---------------- CSR build ----------------

struct EJobs { const int* ei[3]; const float* ew[3]; };

__global__ void k_edge_count(EJobs js, float* deg, int* cnt) {
  int g = blockIdx.y;
  int e = blockIdx.x * blockDim.x + threadIdx.x;
  if (e >= NE) return;
  int dst = js.ei[g][NE + e];
  atomicAdd(&deg[g * NN + dst], js.ew[g][e]);
  atomicAdd(&cnt[g * NN + dst], 1);
}
// per-block sums + dinv. grid (NB79, 3)
__global__ void k_scan_a(const int* __restrict__ cnt, int* __restrict__ part,
                         float* deg) {
  __shared__ int buf[256];
  int g = blockIdx.y, b = blockIdx.x, t = threadIdx.x;
  int i = b * 256 + t;
  if (i < NN) deg[g * NN + i] = rsqrtf(deg[g * NN + i]);   // deg >= 1 (self loop)
  int v = (i < NN) ? cnt[g * NN + i] : 0;
  buf[t] = v;
  __syncthreads();
  for (int off = 128; off > 0; off >>= 1) {
    if (t < off) buf[t] += buf[t + off];
    __syncthreads();
  }
  if (t == 0) part[g * 128 + b] = buf[0];
}
__global__ void k_scan_b(int* part) {
  __shared__ int buf[128];
  int t = threadIdx.x;
  for (int g = 0; g < 3; g++) {
    int v = part[g * 128 + t];
    buf[t] = v;
    __syncthreads();
    for (int off = 1; off < 128; off <<= 1) {
      int u = (t >= off) ? buf[t - off] : 0;
      __syncthreads();
      buf[t] += u;
      __syncthreads();
    }
    part[g * 128 + t] = buf[t] - v;
    __syncthreads();
  }
}
__global__ void k_scan_c(const int* __restrict__ cnt, const int* __restrict__ part,
                         int* __restrict__ offs) {
  __shared__ int buf[256];
  int g = blockIdx.y, b = blockIdx.x, t = threadIdx.x;
  int i = b * 256 + t;
  int v = (i < NN) ? cnt[g * NN + i] : 0;
  buf[t] = v;
  __syncthreads();
  for (int off = 1; off < 256; off <<= 1) {
    int u = (t >= off) ? buf[t - off] : 0;
    __syncthreads();
    buf[t] += u;
    __syncthreads();
  }
  int base = part[g * 128 + b];
  int excl = base + buf[t] - v;
  if (i < NN) offs[g * (NN + 1) + i] = excl;
  if (i == NN - 1) offs[g * (NN + 1) + NN] = excl + v;
}
__global__ void k_fill_csr3(EJobs js, const float* __restrict__ dinv,
                            const int* __restrict__ offs, int* cur,
                            int* csrc, float* cw) {
  int g = blockIdx.y;
  int e = blockIdx.x * blockDim.x + threadIdx.x;
  if (e >= NE) return;
  int s = js.ei[g][e], d = js.ei[g][NE + e];
  float w = js.ew[g][e];
  int pos = offs[g * (NN + 1) + d] + atomicAdd(&cur[g * NN + d], 1);
  csrc[g * NE + pos] = s;
  cw[g * NE + pos] = dinv[g * NN + s] * w * dinv[g * NN + d];
}

// ------- GEMM: bf16 MFMA 128x128 tile, BK=32, double-buffered LDS, 1 barrier/iter -------

__device__ __forceinline__ void gload_lds16(const void* g, void* l) {
  __builtin_amdgcn_global_load_lds((const AS1 void*)g, (AS3 void*)l, 16, 0, 0);
}

struct GemmJob {
  const u16* A; const u16* BT; const float* bias;
  float* outF; u16* outB;
  int lda, ldb, K;
};

template <int NJ>
__global__ __launch_bounds__(256) void k_gemm(GemmJob j0, GemmJob j1, GemmJob j2,
                                              int M, int ldf, int ldob, long obOff,
                                              int xcdswz) {
  GemmJob jb = j0;
  if (NJ > 1 && blockIdx.z == 1) jb = j1;
  if (NJ > 2 && blockIdx.z == 2) jb = j2;
  int m_i, n_i;
  if (xcdswz) {
    // grid (8, 160): XCD = linear%8 owns an m-stripe; n cycles fastest per XCD.
    int L = blockIdx.x + (blockIdx.y << 3);
    int xcd = L & 7, j = L >> 3;
    n_i = j & 7;
    m_i = ((j >> 3) << 3) + xcd;
    if (m_i >= 157) return;
  } else {
    n_i = blockIdx.x; m_i = blockIdx.y;
  }
  const int m0 = m_i * 128, n0 = n_i * 128;

  __shared__ u16 lA[2][4096];
  __shared__ u16 lB[2][4096];
  const int tid = threadIdx.x;
  const int l = tid & 63;
  const int w = tid >> 6;
  const int wr = w >> 1, wc = w & 1;

  f32x4 acc[4][4];
  const f32x4 z = {0.f, 0.f, 0.f, 0.f};
#pragma unroll
  for (int i = 0; i < 4; i++)
#pragma unroll
    for (int j = 0; j < 4; j++) acc[i][j] = z;

  // staging: slot s = q*256+tid -> tile row r=s>>2, k-chunk kc=s&3 (8 elems)
  const u16* gA[2]; const u16* gB[2];
  int ldst[2];
#pragma unroll
  for (int q = 0; q < 2; q++) {
    int s = q * 256 + tid;
    int r = s >> 2, kc = s & 3;
    int ra = m0 + r; if (ra > M - 1) ra = M - 1;
    gA[q] = jb.A + (size_t)ra * jb.lda + kc * 8;
    gB[q] = jb.BT + (size_t)(n0 + r) * jb.ldb + kc * 8;
    ldst[q] = (q * 256 + w * 64) * 8;    // wave-uniform LDS base (elems)
  }

  const int fr = l & 15, qd = l >> 4;
  const int aro[4] = {(wr * 64 + 0 * 16 + fr) * 32 + qd * 8, (wr * 64 + 1 * 16 + fr) * 32 + qd * 8,
                      (wr * 64 + 2 * 16 + fr) * 32 + qd * 8, (wr * 64 + 3 * 16 + fr) * 32 + qd * 8};
  const int bro[4] = {(wc * 64 + 0 * 16 + fr) * 32 + qd * 8, (wc * 64 + 1 * 16 + fr) * 32 + qd * 8,
                      (wc * 64 + 2 * 16 + fr) * 32 + qd * 8, (wc * 64 + 3 * 16 + fr) * 32 + qd * 8};

  const int nit = jb.K >> 5;
  // prologue: stage iter 0 into buf 0
#pragma unroll
  for (int q = 0; q < 2; q++) {
    gload_lds16(gA[q], &lA[0][0] + ldst[q]);
    gload_lds16(gB[q], &lB[0][0] + ldst[q]);
  }
  for (int i = 0; i < nit; i++) {
    __syncthreads();                       // drains stage(i); protects buffers
    if (i + 1 < nit) {
      int nb = (i + 1) & 1, kt = (i + 1) * 32;
#pragma unroll
      for (int q = 0; q < 2; q++) {
        gload_lds16(gA[q] + kt, &lA[nb][0] + ldst[q]);
        gload_lds16(gB[q] + kt, &lB[nb][0] + ldst[q]);
      }
    }
    const u16* la = &lA[i & 1][0];
    const u16* lb = &lB[i & 1][0];
    short8 af[4], bf[4];
#pragma unroll
    for (int t = 0; t < 4; t++) {
      af[t] = *(const short8*)(la + aro[t]);
      bf[t] = *(const short8*)(lb + bro[t]);
    }
#pragma unroll
    for (int i2 = 0; i2 < 4; i2++)
#pragma unroll
      for (int j = 0; j < 4; j++)
        acc[i2][j] = __builtin_amdgcn_mfma_f32_16x16x32_bf16(af[i2], bf[j], acc[i2][j], 0, 0, 0);
  }

#pragma unroll
  for (int i = 0; i < 4; i++) {
#pragma unroll
    for (int r = 0; r < 4; r++) {
      int m = m0 + wr * 64 + i * 16 + qd * 4 + r;
      if (m < M) {
#pragma unroll
        for (int j = 0; j < 4; j++) {
          int n = n0 + wc * 64 + j * 16 + fr;
          float v = acc[i][j][r];
          if (jb.bias) v += jb.bias[n];
          if (jb.outF) jb.outF[(size_t)m * ldf + n] = v;
          if (jb.outB) jb.outB[(size_t)m * ldob + obOff + n] = f2bf(v);
        }
      }
    }
  }
}

// ------- GEMM8: 256x256 tile, BK=64, 8-wave, 4-phase/K-tile counted-vmcnt pipeline -------
// T2 (XOR chunk swizzle, inverse-swizzled global source + swizzled ds_read) +
// T3/T4 (phase-split staging, counted vmcnt placed BEFORE a barrier that precedes
// the dependent reads — vmcnt is per-wave, so cross-wave visibility requires
// wait-then-barrier, read-after-barrier) + T5 (setprio around MFMA clusters).
// Full tiles only: M multiple of 256, K = nkt*64, nkt >= 2.
// LDS A layout (per buf, 32KB): rowgroups {rows 0-63, 128-191 | 64-127, 192-255} x 64 cols.
//   half0 = bytes [0,16K) (read at P0 by wr=0/1), half1 = [16K,32K) (read at P2).
// LDS B layout: h0 = n%64 in [0,32) of each 64-n wave group; h1 = n%64 in [32,64).
// Stage ring (half-tile per phase, 2-K-tile lead):
//   kt.P0: B[kt+1]h1 ; kt.P1: A[kt+2]h0 ; kt.P2: B[kt+2]h0 ; kt.P3: A[kt+2]h1
// Waits: pre-loop WAITV(10)+BAR -> {A,B}[0]h0 visible to all waves at P0.
//   kt.P0: stage, WAITV(8)  (last tile: 0), BAR  -> {A,B}[kt]h1 visible at P1/P2.
//   kt.P3: stage, WAITV(10) (kt==nkt-2: 4), BAR  -> {A,B}[kt+1]h0 visible at next P0.

template <int MS, int NS>
__device__ __forceinline__ void mfma_q(f32x4 (&acc)[8][4], const short8 (&aq)[4][2],
                                       const short8 (&bq)[2][2][2]) {
  __builtin_amdgcn_s_setprio(1);
#pragma unroll
  for (int fm = 0; fm < 4; fm++)
#pragma unroll
    for (int fn = 0; fn < 2; fn++)
#pragma unroll
      for (int kk = 0; kk < 2; kk++)
        acc[MS * 4 + fm][NS * 2 + fn] = __builtin_amdgcn_mfma_f32_16x16x32_bf16(
            aq[fm][kk], bq[NS][fn][kk], acc[MS * 4 + fm][NS * 2 + fn], 0, 0, 0);
  __builtin_amdgcn_s_setprio(0);
}

__device__ __forceinline__ short8 ld8(const char* p) { return *(const short8*)p; }

__global__ __launch_bounds__(512, 2) void k_gemm8(const u16* __restrict__ A,
                                                  const u16* __restrict__ BT,
                                                  u16* __restrict__ outB,
                                                  int lda, int ldb, int ldob, int nkt) {
  __shared__ u16 lA[2][16384];   // 64KB
  __shared__ u16 lB[2][16384];   // 64KB
  // grid (8, 32): xcd = blockIdx.x owns m-stripe of 8 tiles; n cycles within.
  const int m_i = (blockIdx.x << 3) + (blockIdx.y >> 2);
  const int n_i = blockIdx.y & 3;
  const int m0 = m_i * 256, n0 = n_i * 256;
  const int tid = threadIdx.x;
  const int l = tid & 63, w = tid >> 6;
  const int wr = w >> 2, wc = w & 3;        // 2 x 4 waves; wave tile 128 x 64
  const int fr = l & 15, qd = l >> 4;
  const int swzx = (fr & 7) << 4;           // read-side byte XOR

  char* lAc = (char*)&lA[0][0];
  char* lBc = (char*)&lB[0][0];

  // per-thread staging sources + wave-uniform LDS bases, per (half h, q)
  const u16* gAs[2][2]; const u16* gBs[2][2];
  int ldsO[2][2];
#pragma unroll
  for (int h = 0; h < 2; h++)
#pragma unroll
    for (int q = 0; q < 2; q++) {
      int s = q * 512 + tid;                // slot 0..1023
      int lr = s >> 3;                      // lds row within half, 0..127
      int cl = (s & 7) ^ (lr & 7);          // inverse-swizzled source chunk
      int lrow = h * 128 + lr;
      int rgA = lrow >> 6;
      int rA = ((rgA & 1) << 7) + ((rgA >> 1) << 6) + (lrow & 63);
      gAs[h][q] = A + (size_t)(m0 + rA) * lda + cl * 8;
      int wcg = (lrow >> 5) & 3;
      int nB = (wcg << 6) + (h << 5) + (lrow & 31);
      gBs[h][q] = BT + (size_t)(n0 + nB) * ldb + cl * 8;
      ldsO[h][q] = (h << 14) + ((q * 512 + (tid & ~63)) << 4);  // bytes in buf0
    }

#define STG_A(h, bsel, kt2)                                                    \
  do {                                                                         \
    gload_lds16(gAs[h][0] + (kt2) * 64, lAc + ((bsel) << 15) + ldsO[h][0]);    \
    gload_lds16(gAs[h][1] + (kt2) * 64, lAc + ((bsel) << 15) + ldsO[h][1]);    \
  } while (0)
#define STG_B(h, bsel, kt2)                                                    \
  do {                                                                         \
    gload_lds16(gBs[h][0] + (kt2) * 64, lBc + ((bsel) << 15) + ldsO[h][0]);    \
    gload_lds16(gBs[h][1] + (kt2) * 64, lBc + ((bsel) << 15) + ldsO[h][1]);    \
  } while (0)
#define BAR() __builtin_amdgcn_s_barrier()
#define LGKM0()                                                                \
  do {                                                                         \
    asm volatile("s_waitcnt lgkmcnt(0)" ::: "memory");                         \
    __builtin_amdgcn_sched_barrier(0);                                         \
  } while (0)
#define WAITV(N) asm volatile("s_waitcnt vmcnt(" #N ")" ::: "memory")

  f32x4 acc[8][4];
  const f32x4 z = {0.f, 0.f, 0.f, 0.f};
#pragma unroll
  for (int i = 0; i < 8; i++)
#pragma unroll
    for (int j = 0; j < 4; j++) acc[i][j] = z;

  short8 aq[4][2];      // current msub A-frags [fmL][kk]
  short8 bq[2][2][2];   // B-frags [nsub][fnL][kk]

  // read-address constants (bytes)
  const int aB = (wr << 13) + (fr << 7);    // rowgroup-base(wr) + fr row
  const int bB = (wc << 12) + (fr << 7);
  const int colb0 = ((qd << 4)) ^ swzx;           // kk=0
  const int colb1 = (64 + (qd << 4)) ^ swzx;      // kk=1

  // prologue: 7 half-tile stages (14 loads/thread), then wait+barrier so that
  // every wave's {A,B}[0]h0 shares are in LDS before any wave reads them.
  STG_A(0, 0, 0); STG_B(0, 0, 0); STG_A(1, 0, 0); STG_B(1, 0, 0);
  STG_A(0, 1, 1); STG_B(0, 1, 1); STG_A(1, 1, 1);
  WAITV(10);
  BAR();

  for (int kt = 0; kt < nkt; ++kt) {
    const int buf = kt & 1, nb = buf ^ 1;
    const int bo = buf << 15;
    // ---- P0: Q(msub0, nsub0); 12 ds_reads; stage B[kt+1]h1; wait {A,B}[kt]h1
#pragma unroll
    for (int fmL = 0; fmL < 4; fmL++) {
      aq[fmL][0] = ld8(lAc + bo + aB + (fmL << 11) + colb0);
      aq[fmL][1] = ld8(lAc + bo + aB + (fmL << 11) + colb1);
    }
#pragma unroll
    for (int fnL = 0; fnL < 2; fnL++) {
      bq[0][fnL][0] = ld8(lBc + bo + bB + (fnL << 11) + colb0);
      bq[0][fnL][1] = ld8(lBc + bo + bB + (fnL << 11) + colb1);
    }
    if (kt + 1 < nkt) { STG_B(1, nb, kt + 1); }
    if (kt == nkt - 1) { WAITV(0); } else { WAITV(8); }
    BAR(); LGKM0();
    mfma_q<0, 0>(acc, aq, bq);
    BAR();
    // ---- P1: Q(msub0, nsub1); 4 ds_reads; stage A[kt+2]h0
#pragma unroll
    for (int fnL = 0; fnL < 2; fnL++) {
      bq[1][fnL][0] = ld8(lBc + bo + bB + (1 << 14) + (fnL << 11) + colb0);
      bq[1][fnL][1] = ld8(lBc + bo + bB + (1 << 14) + (fnL << 11) + colb1);
    }
    if (kt + 2 < nkt) { STG_A(0, buf, kt + 2); }
    BAR(); LGKM0();
    mfma_q<0, 1>(acc, aq, bq);
    BAR();
    // ---- P2: Q(msub1, nsub1); 8 ds_reads (A msub1); stage B[kt+2]h0
#pragma unroll
    for (int fmL = 0; fmL < 4; fmL++) {
      aq[fmL][0] = ld8(lAc + bo + aB + (1 << 14) + (fmL << 11) + colb0);
      aq[fmL][1] = ld8(lAc + bo + aB + (1 << 14) + (fmL << 11) + colb1);
    }
    if (kt + 2 < nkt) { STG_B(0, buf, kt + 2); }
    BAR(); LGKM0();
    mfma_q<1, 1>(acc, aq, bq);
    BAR();
    // ---- P3: Q(msub1, nsub0); no ds_reads; stage A[kt+2]h1; wait {A,B}[kt+1]h0
    if (kt + 2 < nkt) { STG_A(1, buf, kt + 2); }
    if (kt < nkt - 2) { WAITV(10); }
    else if (kt == nkt - 2) { WAITV(4); }
    BAR(); LGKM0();
    mfma_q<1, 0>(acc, aq, bq);
    BAR();
  }

#undef STG_A
#undef STG_B
#undef BAR
#undef LGKM0
#undef WAITV

  // epilogue: full tiles, no guards
  const int mBase = m0 + wr * 128 + qd * 4;
  const int nBase = n0 + wc * 64 + fr;
#pragma unroll
  for (int fm = 0; fm < 8; fm++)
#pragma unroll
    for (int fn = 0; fn < 4; fn++)
#pragma unroll
      for (int r = 0; r < 4; r++)
        outB[(size_t)(mBase + fm * 16 + r) * ldob + nBase + fn * 16] = f2bf(acc[fm][fn][r]);
}

// ---------------- aggregation (pull, wave per node) ----------------

struct AggJob {
  const u16* H;
  const int* offs; const int* csrc; const float* cw; const float* dinv;
  const float* bias;
  float* outF; u16* outB;
  long obOff; int colOff;
};

template <int CPL>
__global__ void k_agg(AggJob j0, AggJob j1, AggJob j2, int ldh, int ldf, int ldob,
                      int relu) {
  AggJob jb = j0;
  if (blockIdx.y == 1) jb = j1;
  if (blockIdx.y == 2) jb = j2;
  int wid = blockIdx.x * (blockDim.x >> 6) + (threadIdx.x >> 6);
  if (wid >= NN) return;
  int l = threadIdx.x & 63;
  const u16* hbase = jb.H + jb.colOff + (size_t)l * CPL;
  float acc[CPL], f0[CPL], f1[CPL];
  float dv = jb.dinv[wid];
  float sw = dv * dv;
  if (CPL == 8) ld_bf16x8(hbase + (size_t)wid * ldh, f0);
  else          ld_bf16x4(hbase + (size_t)wid * ldh, f0);
#pragma unroll
  for (int j = 0; j < CPL; j++) acc[j] = f0[j] * sw;
  int e = jb.offs[wid], e1 = jb.offs[wid + 1];
  for (; e + 2 <= e1; e += 2) {
    int s0 = jb.csrc[e], s1 = jb.csrc[e + 1];
    float w0 = jb.cw[e], w1 = jb.cw[e + 1];
    if (CPL == 8) { ld_bf16x8(hbase + (size_t)s0 * ldh, f0); ld_bf16x8(hbase + (size_t)s1 * ldh, f1); }
    else          { ld_bf16x4(hbase + (size_t)s0 * ldh, f0); ld_bf16x4(hbase + (size_t)s1 * ldh, f1); }
#pragma unroll
    for (int j = 0; j < CPL; j++) acc[j] += f0[j] * w0;
#pragma unroll
    for (int j = 0; j < CPL; j++) acc[j] += f1[j] * w1;
  }
  if (e < e1) {
    int s0 = jb.csrc[e];
    float w0 = jb.cw[e];
    if (CPL == 8) ld_bf16x8(hbase + (size_t)s0 * ldh, f0);
    else          ld_bf16x4(hbase + (size_t)s0 * ldh, f0);
#pragma unroll
    for (int j = 0; j < CPL; j++) acc[j] += f0[j] * w0;
  }
  const float* bp = jb.bias + l * CPL;
#pragma unroll
  for (int j = 0; j < CPL; j++) {
    float v = acc[j] + bp[j];
    if (relu) v = v > 0.f ? v : 0.f;
    acc[j] = v;
  }
  if (jb.outF) {
    float* q = jb.outF + (size_t)wid * ldf + l * CPL;
#pragma unroll
    for (int j = 0; j < CPL; j++) q[j] = acc[j];
  }
  if (jb.outB) {
    u16* q = jb.outB + (size_t)wid * ldob + jb.obOff + l * CPL;
#pragma unroll
    for (int j = 0; j < CPL; j++) q[j] = f2bf(acc[j]);
  }
}

// ---------------- launch ----------------

extern "C" void kernel_launch(void* const* d_in, const int* in_sizes, int n_in,
                              void* d_out, int out_size, void* d_ws, size_t ws_size,
                              hipStream_t stream) {
  (void)in_sizes; (void)n_in; (void)out_size; (void)ws_size;
  const float* x_RNA = (const float*)d_in[0];
  const float* x_ADT = (const float*)d_in[1];
  EJobs ej;
  ej.ei[0] = (const int*)d_in[2]; ej.ew[0] = (const float*)d_in[3];
  ej.ei[1] = (const int*)d_in[4]; ej.ew[1] = (const float*)d_in[5];
  ej.ei[2] = (const int*)d_in[6]; ej.ew[2] = (const float*)d_in[7];
  const float* W_rna1 = (const float*)d_in[8];  const float* b_rna1 = (const float*)d_in[9];
  const float* W_rna2 = (const float*)d_in[10]; const float* b_rna2 = (const float*)d_in[11];
  const float* W_p3   = (const float*)d_in[12]; const float* b_p3   = (const float*)d_in[13];
  const float* W_sim  = (const float*)d_in[14]; const float* b_sim  = (const float*)d_in[15];
  const float* W_dist = (const float*)d_in[16]; const float* b_dist = (const float*)d_in[17];
  const float* W_f1   = (const float*)d_in[18]; const float* b_f1   = (const float*)d_in[19];
  const float* W_f2   = (const float*)d_in[20]; const float* b_f2   = (const float*)d_in[21];
  float* out = (float*)d_out;

  char* p = (char*)d_ws;
  auto alloc = [&](size_t bytes) {
    char* r = p;
    p += (bytes + 255) & ~(size_t)255;
    return r;
  };
  u16* WcT   = (u16*)alloc((size_t)1024 * KX * 2);
  u16* WsT   = (u16*)alloc((size_t)OUTC * HID * 2);
  u16* WdT   = (u16*)alloc((size_t)OUTC * HID * 2);
  u16* Wf1T  = (u16*)alloc((size_t)OUTC * HID * 2);
  u16* Wp3T  = (u16*)alloc((size_t)OUTC * KQ * 2);
  u16* WcatT = (u16*)alloc((size_t)OUTC * 768 * 2);
  float* bias2 = (float*)alloc(OUTC * 4);
  u16* ADTb = (u16*)alloc((size_t)NN * KQ * 2);
  u16* H1   = (u16*)alloc((size_t)NN * 1024 * 2);  // later: H2s|H2d|H2p
  u16* B2   = (u16*)alloc((size_t)NN * 1024 * 2);  // XS|XD, later XSDP
  float* deg = (float*)alloc((size_t)3 * NN * 4);
  int* cnt   = (int*)alloc((size_t)3 * NN * 4);
  int* offs  = (int*)alloc((size_t)3 * (NN + 1) * 4);
  int* cur   = (int*)alloc((size_t)3 * NN * 4);
  int* csrc  = (int*)alloc((size_t)3 * NE * 4);
  float* cwn = (float*)alloc((size_t)3 * NE * 4);
  int* part  = (int*)alloc(3 * 128 * 4);

  u16* Xb   = (u16*)d_out;   // bf16 x_RNA scratch: dead before first f32 output write
  u16* XS   = B2;
  u16* XD   = B2 + (size_t)NN * 512;
  u16* XSDP = B2;            // [NN, 768] = x_sim | x_dist | pro (bf16), after A2
  u16* H2s  = H1;
  u16* H2d  = H1 + (size_t)NN * 256;
  u16* H2p  = H1 + (size_t)NN * 512;

  const int T = 256;
  Prep P;
  P.xR = x_RNA; P.xA = x_ADT; P.W1 = W_rna1; P.W2 = W_rna2;
  P.Ws0 = W_sim; P.Ws1 = W_dist; P.Ws2 = W_f1; P.Ws3 = W_f2; P.Ws4 = W_p3;
  P.Wo0 = WsT; P.Wo1 = WdT; P.Wo2 = Wf1T; P.Wo3 = nullptr; P.Wo4 = Wp3T;
  P.bf1 = b_f1; P.bf2 = b_f2;
  P.Xb = Xb; P.ADTb = ADTb; P.WcT = WcT; P.WcatT = WcatT; P.bias2 = bias2;
  P.deg = deg; P.cnt = cnt; P.cur = cur;
  P.Wo3 = (u16*)(cwn);  // dead scratch until k_fill_csr3; wT5 finishes in k_prep before it
  k_prep<<<23038, T, 0, stream>>>(P);

  k_edge_count<<<dim3((NE + T - 1) / T, 3), T, 0, stream>>>(ej, deg, cnt);
  k_scan_a<<<dim3(NB79, 3), 256, 0, stream>>>(cnt, part, deg);
  k_scan_b<<<1, 128, 0, stream>>>(part);
  k_scan_c<<<dim3(NB79, 3), 256, 0, stream>>>(cnt, part, offs);
  k_fill_csr3<<<dim3((NE + T - 1) / T, 3), T, 0, stream>>>(ej, deg, offs, cur, csrc, cwn);

  GemmJob jz = {};
  // G1 main: rows [0,16384) = 64 full 256-tiles x 4 n-tiles = 256 blocks (1 round, 1 blk/CU)
  k_gemm8<<<dim3(8, 32), 512, 0, stream>>>(Xb, WcT, H1, KX, KX, 1024, KX >> 6);
  // G1 tail: rows [16384,20000) on the 128^2 kernel (29 x 8 = 232 blocks)
  GemmJob g1t = {Xb + (size_t)16384 * KX, WcT, nullptr, nullptr, H1 + (size_t)16384 * 1024,
                 KX, KX, KX};
  k_gemm<1><<<dim3(8, 29), 256, 0, stream>>>(g1t, jz, jz, NN - 16384, 0, 1024, 0, 0);
  // A1: XS = relu(agg_sim(H1[:,:512]) + b_rna1); XD likewise (dist)
  AggJob a0 = {H1, offs, csrc, cwn, deg, b_rna1, nullptr, XS, 0, 0};
  AggJob a1 = {H1, offs + (NN + 1), csrc + NE, cwn + NE, deg + NN, b_rna2, nullptr, XD, 0, 512};
  k_agg<8><<<dim3(NN / 4, 2), 256, 0, stream>>>(a0, a1, a1, 1024, 0, 512, 1);
  // G2: H2s=XS@W_sim, H2d=XD@W_dist, H2p=ADTb@W_p3
  GemmJob g2a = {XS, WsT, nullptr, nullptr, H2s, HID, HID, HID};
  GemmJob g2b = {XD, WdT, nullptr, nullptr, H2d, HID, HID, HID};
  GemmJob g2c = {ADTb, Wp3T, nullptr, nullptr, H2p, KQ, KQ, KQ};
  k_gemm<3><<<dim3(2, 157, 3), 256, 0, stream>>>(g2a, g2b, g2c, NN, 0, 256, 0, 0);
  // A2: x_sim, x_dist, pro -> f32 outputs + bf16 into XSDP
  AggJob b0 = {H2s, offs, csrc, cwn, deg, b_sim, out, XSDP, 0, 0};
  AggJob b1 = {H2d, offs + (NN + 1), csrc + NE, cwn + NE, deg + NN, b_dist,
               out + OUTSZ, XSDP, 256, 0};
  AggJob b2 = {H2p, offs + 2 * (NN + 1), csrc + 2 * NE, cwn + 2 * NE, deg + 2 * NN, b_p3,
               out + 4 * OUTSZ, XSDP, 512, 0};
  k_agg<4><<<dim3(NN / 4, 3), 256, 0, stream>>>(b0, b1, b2, 256, 256, 768, 0);
  // G5 (2 jobs): fused = XSDP[:,:512]@W_f1 + b_f1 ; fused_pro = XSDP@Wcat + bias2
  GemmJob g5a = {XSDP, Wf1T, b_f1, out + 2 * OUTSZ, nullptr, 768, 512, 512};
  GemmJob g5b = {XSDP, WcatT, bias2, out + 3 * OUTSZ, nullptr, 768, 768, 768};
  k_gemm<2><<<dim3(2, 157, 2), 256, 0, stream>>>(g5a, g5b, jz, NN, 256, 0, 0, 0);
}

// Round 3
// 834.336 us; speedup vs baseline: 1.0097x; 1.0097x over previous
//
#include <hip/hip_runtime.h>

#define AS1 __attribute__((address_space(1)))
#define AS3 __attribute__((address_space(3)))

typedef __attribute__((ext_vector_type(8))) short short8;
typedef __attribute__((ext_vector_type(4))) float f32x4;
typedef unsigned int u32;
typedef unsigned short u16;

static constexpr int NN = 20000;
static constexpr int NE = 320000;
static constexpr int INC = 2000;
static constexpr int KX = 2048;
static constexpr int HID = 512;
static constexpr int OUTC = 256;
static constexpr int QA = 100;
static constexpr int KQ = 128;
static constexpr long OUTSZ = (long)NN * OUTC;
static constexpr int NB79 = (NN + 255) / 256;   // 79

__device__ __forceinline__ u16 f2bf(float f) {
  u32 u = __float_as_uint(f);
  u = (u + 0x7FFFu + ((u >> 16) & 1u)) >> 16;   // RNE
  return (u16)u;
}
__device__ __forceinline__ void ld_bf16x8(const u16* p, float* f) {
  uint4 r = *(const uint4*)p;
  f[0] = __uint_as_float(r.x << 16); f[1] = __uint_as_float(r.x & 0xFFFF0000u);
  f[2] = __uint_as_float(r.y << 16); f[3] = __uint_as_float(r.y & 0xFFFF0000u);
  f[4] = __uint_as_float(r.z << 16); f[5] = __uint_as_float(r.z & 0xFFFF0000u);
  f[6] = __uint_as_float(r.w << 16); f[7] = __uint_as_float(r.w & 0xFFFF0000u);
}
__device__ __forceinline__ void ld_bf16x4(const u16* p, float* f) {
  uint2 r = *(const uint2*)p;
  f[0] = __uint_as_float(r.x << 16); f[1] = __uint_as_float(r.x & 0xFFFF0000u);
  f[2] = __uint_as_float(r.y << 16); f[3] = __uint_as_float(r.y & 0xFFFF0000u);
}

// ---------------- fused prep kernel ----------------
// Round order: latency-bound small rounds FIRST (low block IDs dispatch first and
// overlap R0's BW phase instead of forming a serial tail).
// R4 [0,769): Wcat compose + bias2 (LDS row + 8-acc MLP)
// R2 [769,1041): 5 small-weight transposes
// R3 [1041,1553): WcT LDS transpose
// R5 [1553,1788): CSR state init
// R1 [1788,3038): x_ADT cast (16 rows/blk)
// R0 [3038,23038): x_RNA row cast->Xb (BW-dominant)
struct Prep {
  const float *xR, *xA;
  const float *W1, *W2;                     // W_rna1, W_rna2
  const float *Ws0, *Ws1, *Ws2, *Ws3, *Ws4; // W_sim, W_dist, W_f1, W_f2, W_p3
  u16 *Wo0, *Wo1, *Wo2, *Wo3, *Wo4;
  const float *bf1, *bf2;
  u16 *Xb, *ADTb, *WcT, *WcatT;
  float *bias2;
  float *deg; int *cnt; int *cur;
};

__global__ __launch_bounds__(256) void k_prep(Prep P) {
  int b = blockIdx.x, t = threadIdx.x;
  if (b < 769) {                         // ---- R4: Wcat compose
    int k = b, n = t;
    if (k < 512) {
      __shared__ float w2row[256];
      w2row[t] = P.Ws2[k * OUTC + t];
      __syncthreads();
      float s0 = 0.f, s1 = 0.f, s2 = 0.f, s3 = 0.f;
      float s4 = 0.f, s5 = 0.f, s6 = 0.f, s7 = 0.f;
      for (int j = 0; j < 256; j += 8) {
        s0 += w2row[j + 0] * P.Ws3[(j + 0) * OUTC + n];
        s1 += w2row[j + 1] * P.Ws3[(j + 1) * OUTC + n];
        s2 += w2row[j + 2] * P.Ws3[(j + 2) * OUTC + n];
        s3 += w2row[j + 3] * P.Ws3[(j + 3) * OUTC + n];
        s4 += w2row[j + 4] * P.Ws3[(j + 4) * OUTC + n];
        s5 += w2row[j + 5] * P.Ws3[(j + 5) * OUTC + n];
        s6 += w2row[j + 6] * P.Ws3[(j + 6) * OUTC + n];
        s7 += w2row[j + 7] * P.Ws3[(j + 7) * OUTC + n];
      }
      float s = ((s0 + s1) + (s2 + s3)) + ((s4 + s5) + (s6 + s7));
      P.WcatT[(long)n * 768 + k] = f2bf(s);
    } else if (k < 768) {
      P.WcatT[(long)n * 768 + k] = f2bf(P.Ws3[(256 + k - 512) * OUTC + n]);
    } else {
      float s0 = 0.f, s1 = 0.f, s2 = 0.f, s3 = 0.f;
      for (int j = 0; j < 256; j += 4) {
        s0 += P.bf1[j + 0] * P.Ws3[(j + 0) * OUTC + n];
        s1 += P.bf1[j + 1] * P.Ws3[(j + 1) * OUTC + n];
        s2 += P.bf1[j + 2] * P.Ws3[(j + 2) * OUTC + n];
        s3 += P.bf1[j + 3] * P.Ws3[(j + 3) * OUTC + n];
      }
      P.bias2[n] = P.bf2[n] + ((s0 + s1) + (s2 + s3));
    }
    return;
  }
  if (b < 1041) {                        // ---- R2: wT5
    int slot = (b - 769) * 256 + t;
    const float* W; u16* o; int Kin, Kpad, within;
    if (slot < 65536) {
      int j = slot >> 14; within = slot & 16383;
      W = (j == 0) ? P.Ws0 : (j == 1) ? P.Ws1 : (j == 2) ? P.Ws2 : P.Ws3;
      o = (j == 0) ? P.Wo0 : (j == 1) ? P.Wo1 : (j == 2) ? P.Wo2 : P.Wo3;
      Kin = HID; Kpad = HID;
    } else {
      within = slot - 65536; W = P.Ws4; o = P.Wo4; Kin = QA; Kpad = KQ;
    }
    int kg = Kpad >> 3;
    int n = within / kg, k8 = (within % kg) << 3;
    u16 v[8];
#pragma unroll
    for (int j = 0; j < 8; j++) {
      int k = k8 + j;
      v[j] = (k < Kin) ? f2bf(W[(long)k * OUTC + n]) : (u16)0;
    }
    *(uint4*)(o + (long)n * Kpad + k8) = *(const uint4*)v;
    return;
  }
  if (b < 1553) {                        // ---- R3: WcT transpose
    __shared__ float tile[64][65];
    int bb = b - 1041;
    int kb = (bb & 31) * 64, nb = (bb >> 5) * 64;
    const float* W = (nb < HID) ? P.W1 : P.W2;
    int nb2 = nb & (HID - 1);
#pragma unroll
    for (int p = 0; p < 4; p++) {
      int idx = p * 256 + t;
      int r = idx >> 4, c4 = (idx & 15) << 2;
      int k = kb + r;
      float4 v = {0.f, 0.f, 0.f, 0.f};
      if (k < INC) v = *(const float4*)(W + (long)k * HID + nb2 + c4);
      tile[r][c4] = v.x; tile[r][c4 + 1] = v.y; tile[r][c4 + 2] = v.z; tile[r][c4 + 3] = v.w;
    }
    __syncthreads();
#pragma unroll
    for (int p = 0; p < 2; p++) {
      int idx = p * 256 + t;
      int n = idx >> 3, kg = (idx & 7) << 3;
      u16 v[8];
#pragma unroll
      for (int j = 0; j < 8; j++) v[j] = f2bf(tile[kg + j][n]);
      *(uint4*)(P.WcT + (long)(nb + n) * KX + kb + kg) = *(const uint4*)v;
    }
    return;
  }
  if (b < 1788) {                        // ---- R5: CSR init
    int i = (b - 1553) * 256 + t;
    if (i < 3 * NN) { P.deg[i] = 1.0f; P.cnt[i] = 0; P.cur[i] = 0; }
    return;
  }
  if (b < 3038) {                        // ---- R1: x_ADT cast, 16 rows/block
    int row = (b - 1788) * 16 + (t >> 4);
    int c8 = (t & 15) << 3;
    u16 v[8];
#pragma unroll
    for (int j = 0; j < 8; j++) {
      int c = c8 + j;
      v[j] = (c < QA) ? f2bf(P.xA[(long)row * QA + c]) : (u16)0;
    }
    *(uint4*)(P.ADTb + (long)row * KQ + c8) = *(const uint4*)v;
    return;
  }
  {                                      // ---- R0: x_RNA row cast
    int row = b - 3038;
    int c8 = t << 3;
    u16 v[8];
    if (c8 + 8 <= INC) {
      const float4* p = (const float4*)(P.xR + (long)row * INC + c8);
      float4 a = p[0], c = p[1];
      v[0] = f2bf(a.x); v[1] = f2bf(a.y); v[2] = f2bf(a.z); v[3] = f2bf(a.w);
      v[4] = f2bf(c.x); v[5] = f2bf(c.y); v[6] = f2bf(c.z); v[7] = f2bf(c.w);
    } else {
#pragma unroll
      for (int j = 0; j < 8; j++) {
        int c = c8 + j;
        v[j] = (c < INC) ? f2bf(P.xR[(long)row * INC + c]) : (u16)0;
      }
    }
    *(uint4*)(P.Xb + (long)row * KX + c8) = *(const uint4*)v;
  }
}

// ---------------- CSR build ----------------

struct EJobs { const int* ei[3]; const float* ew[3]; };

__global__ void k_edge_count(EJobs js, float* deg, int* cnt) {
  int g = blockIdx.y;
  int e = blockIdx.x * blockDim.x + threadIdx.x;
  if (e >= NE) return;
  int dst = js.ei[g][NE + e];
  atomicAdd(&deg[g * NN + dst], js.ew[g][e]);
  atomicAdd(&cnt[g * NN + dst], 1);
}
// per-block sums + dinv. grid (NB79, 3)
__global__ void k_scan_a(const int* __restrict__ cnt, int* __restrict__ part,
                         float* deg) {
  __shared__ int buf[256];
  int g = blockIdx.y, b = blockIdx.x, t = threadIdx.x;
  int i = b * 256 + t;
  if (i < NN) deg[g * NN + i] = rsqrtf(deg[g * NN + i]);   // deg >= 1 (self loop)
  int v = (i < NN) ? cnt[g * NN + i] : 0;
  buf[t] = v;
  __syncthreads();
  for (int off = 128; off > 0; off >>= 1) {
    if (t < off) buf[t] += buf[t + off];
    __syncthreads();
  }
  if (t == 0) part[g * 128 + b] = buf[0];
}
__global__ void k_scan_b(int* part) {
  __shared__ int buf[128];
  int t = threadIdx.x;
  for (int g = 0; g < 3; g++) {
    int v = part[g * 128 + t];
    buf[t] = v;
    __syncthreads();
    for (int off = 1; off < 128; off <<= 1) {
      int u = (t >= off) ? buf[t - off] : 0;
      __syncthreads();
      buf[t] += u;
      __syncthreads();
    }
    part[g * 128 + t] = buf[t] - v;
    __syncthreads();
  }
}
__global__ void k_scan_c(const int* __restrict__ cnt, const int* __restrict__ part,
                         int* __restrict__ offs) {
  __shared__ int buf[256];
  int g = blockIdx.y, b = blockIdx.x, t = threadIdx.x;
  int i = b * 256 + t;
  int v = (i < NN) ? cnt[g * NN + i] : 0;
  buf[t] = v;
  __syncthreads();
  for (int off = 1; off < 256; off <<= 1) {
    int u = (t >= off) ? buf[t - off] : 0;
    __syncthreads();
    buf[t] += u;
    __syncthreads();
  }
  int base = part[g * 128 + b];
  int excl = base + buf[t] - v;
  if (i < NN) offs[g * (NN + 1) + i] = excl;
  if (i == NN - 1) offs[g * (NN + 1) + NN] = excl + v;
}
__global__ void k_fill_csr3(EJobs js, const float* __restrict__ dinv,
                            const int* __restrict__ offs, int* cur,
                            int* csrc, float* cw) {
  int g = blockIdx.y;
  int e = blockIdx.x * blockDim.x + threadIdx.x;
  if (e >= NE) return;
  int s = js.ei[g][e], d = js.ei[g][NE + e];
  float w = js.ew[g][e];
  int pos = offs[g * (NN + 1) + d] + atomicAdd(&cur[g * NN + d], 1);
  csrc[g * NE + pos] = s;
  cw[g * NE + pos] = dinv[g * NN + s] * w * dinv[g * NN + d];
}

// ------- GEMM: bf16 MFMA 128x128 tile, BK=32, double-buffered LDS, 1 barrier/iter -------

__device__ __forceinline__ void gload_lds16(const void* g, void* l) {
  __builtin_amdgcn_global_load_lds((const AS1 void*)g, (AS3 void*)l, 16, 0, 0);
}

struct GemmJob {
  const u16* A; const u16* BT; const float* bias;
  float* outF; u16* outB;
  int lda, ldb, K;
};

template <int NJ>
__global__ __launch_bounds__(256) void k_gemm(GemmJob j0, GemmJob j1, GemmJob j2,
                                              int M, int ldf, int ldob, long obOff,
                                              int xcdswz) {
  GemmJob jb = j0;
  if (NJ > 1 && blockIdx.z == 1) jb = j1;
  if (NJ > 2 && blockIdx.z == 2) jb = j2;
  int m_i, n_i;
  if (xcdswz) {
    // grid (8, 160): XCD = linear%8 owns an m-stripe; n cycles fastest per XCD.
    int L = blockIdx.x + (blockIdx.y << 3);
    int xcd = L & 7, j = L >> 3;
    n_i = j & 7;
    m_i = ((j >> 3) << 3) + xcd;
    if (m_i >= 157) return;
  } else {
    n_i = blockIdx.x; m_i = blockIdx.y;
  }
  const int m0 = m_i * 128, n0 = n_i * 128;

  __shared__ u16 lA[2][4096];
  __shared__ u16 lB[2][4096];
  const int tid = threadIdx.x;
  const int l = tid & 63;
  const int w = tid >> 6;
  const int wr = w >> 1, wc = w & 1;

  f32x4 acc[4][4];
  const f32x4 z = {0.f, 0.f, 0.f, 0.f};
#pragma unroll
  for (int i = 0; i < 4; i++)
#pragma unroll
    for (int j = 0; j < 4; j++) acc[i][j] = z;

  // staging: slot s = q*256+tid -> tile row r=s>>2, k-chunk kc=s&3 (8 elems)
  const u16* gA[2]; const u16* gB[2];
  int ldst[2];
#pragma unroll
  for (int q = 0; q < 2; q++) {
    int s = q * 256 + tid;
    int r = s >> 2, kc = s & 3;
    int ra = m0 + r; if (ra > M - 1) ra = M - 1;
    gA[q] = jb.A + (size_t)ra * jb.lda + kc * 8;
    gB[q] = jb.BT + (size_t)(n0 + r) * jb.ldb + kc * 8;
    ldst[q] = (q * 256 + w * 64) * 8;    // wave-uniform LDS base (elems)
  }

  const int fr = l & 15, qd = l >> 4;
  const int aro[4] = {(wr * 64 + 0 * 16 + fr) * 32 + qd * 8, (wr * 64 + 1 * 16 + fr) * 32 + qd * 8,
                      (wr * 64 + 2 * 16 + fr) * 32 + qd * 8, (wr * 64 + 3 * 16 + fr) * 32 + qd * 8};
  const int bro[4] = {(wc * 64 + 0 * 16 + fr) * 32 + qd * 8, (wc * 64 + 1 * 16 + fr) * 32 + qd * 8,
                      (wc * 64 + 2 * 16 + fr) * 32 + qd * 8, (wc * 64 + 3 * 16 + fr) * 32 + qd * 8};

  const int nit = jb.K >> 5;
  // prologue: stage iter 0 into buf 0
#pragma unroll
  for (int q = 0; q < 2; q++) {
    gload_lds16(gA[q], &lA[0][0] + ldst[q]);
    gload_lds16(gB[q], &lB[0][0] + ldst[q]);
  }
  for (int i = 0; i < nit; i++) {
    __syncthreads();                       // drains stage(i); protects buffers
    if (i + 1 < nit) {
      int nb = (i + 1) & 1, kt = (i + 1) * 32;
#pragma unroll
      for (int q = 0; q < 2; q++) {
        gload_lds16(gA[q] + kt, &lA[nb][0] + ldst[q]);
        gload_lds16(gB[q] + kt, &lB[nb][0] + ldst[q]);
      }
    }
    const u16* la = &lA[i & 1][0];
    const u16* lb = &lB[i & 1][0];
    short8 af[4], bf[4];
#pragma unroll
    for (int t = 0; t < 4; t++) {
      af[t] = *(const short8*)(la + aro[t]);
      bf[t] = *(const short8*)(lb + bro[t]);
    }
#pragma unroll
    for (int i2 = 0; i2 < 4; i2++)
#pragma unroll
      for (int j = 0; j < 4; j++)
        acc[i2][j] = __builtin_amdgcn_mfma_f32_16x16x32_bf16(af[i2], bf[j], acc[i2][j], 0, 0, 0);
  }

#pragma unroll
  for (int i = 0; i < 4; i++) {
#pragma unroll
    for (int r = 0; r < 4; r++) {
      int m = m0 + wr * 64 + i * 16 + qd * 4 + r;
      if (m < M) {
#pragma unroll
        for (int j = 0; j < 4; j++) {
          int n = n0 + wc * 64 + j * 16 + fr;
          float v = acc[i][j][r];
          if (jb.bias) v += jb.bias[n];
          if (jb.outF) jb.outF[(size_t)m * ldf + n] = v;
          if (jb.outB) jb.outB[(size_t)m * ldob + obOff + n] = f2bf(v);
        }
      }
    }
  }
}

// ------- GEMM8: 256x256 tile, BK=64, 8-wave, 4-phase/K-tile counted-vmcnt pipeline -------
// Schedule identical to round-2 (verified correct). This round: VGPR-pressure trim —
// the 16 staging pointers collapse to 2 bases + uniform scalar offsets
// (q: +128 rows; A h: +64 rows; B h: +32 rows), ldsO collapses to ldsW + literals.
// Waits: pre-loop WAITV(10)+BAR -> {A,B}[0]h0 visible to all waves at P0.
//   kt.P0: stage, WAITV(8)  (last tile: 0), BAR  -> {A,B}[kt]h1 visible at P1/P2.
//   kt.P3: stage, WAITV(10) (kt==nkt-2: 4), BAR  -> {A,B}[kt+1]h0 visible at next P0.

template <int MS, int NS>
__device__ __forceinline__ void mfma_q(f32x4 (&acc)[8][4], const short8 (&aq)[4][2],
                                       const short8 (&bq)[2][2][2]) {
  __builtin_amdgcn_s_setprio(1);
#pragma unroll
  for (int fm = 0; fm < 4; fm++)
#pragma unroll
    for (int fn = 0; fn < 2; fn++)
#pragma unroll
      for (int kk = 0; kk < 2; kk++)
        acc[MS * 4 + fm][NS * 2 + fn] = __builtin_amdgcn_mfma_f32_16x16x32_bf16(
            aq[fm][kk], bq[NS][fn][kk], acc[MS * 4 + fm][NS * 2 + fn], 0, 0, 0);
  __builtin_amdgcn_s_setprio(0);
}

__device__ __forceinline__ short8 ld8(const char* p) { return *(const short8*)p; }

__global__ __launch_bounds__(512, 2) void k_gemm8(const u16* __restrict__ A,
                                                  const u16* __restrict__ BT,
                                                  u16* __restrict__ outB,
                                                  int lda, int ldb, int ldob, int nkt) {
  __shared__ u16 lA[2][16384];   // 64KB
  __shared__ u16 lB[2][16384];   // 64KB
  // grid (8, 32): xcd = blockIdx.x owns m-stripe of 8 tiles; n cycles within.
  const int m_i = (blockIdx.x << 3) + (blockIdx.y >> 2);
  const int n_i = blockIdx.y & 3;
  const int m0 = m_i * 256, n0 = n_i * 256;
  const int tid = threadIdx.x;
  const int l = tid & 63, w = tid >> 6;
  const int wr = w >> 2, wc = w & 3;        // 2 x 4 waves; wave tile 128 x 64
  const int fr = l & 15, qd = l >> 4;
  const int swzx = (fr & 7) << 4;           // read-side byte XOR

  char* lAc = (char*)&lA[0][0];
  char* lBc = (char*)&lB[0][0];

  const size_t ldaS = (size_t)lda, ldbS = (size_t)ldb;
  // staging bases: slot s = q*512+tid; lr = s>>3 (row in half), cl = (s&7)^(lr&7).
  // For q=0 (lr<64): rA=lr, nB=(lr>>5)*64+(lr&31); cl identical for q=0/1 since 64&7==0.
  // Derived offsets (elements): q=1 -> +128 rows; A h=1 -> +64 rows; B h=1 -> +32 rows.
  const int lr = tid >> 3;
  const int cl = (tid & 7) ^ (lr & 7);
  const u16* gA0 = A + (size_t)(m0 + lr) * ldaS + cl * 8;
  const u16* gB0 = BT + (size_t)(n0 + ((lr >> 5) << 6) + (lr & 31)) * ldbS + cl * 8;
  const int ldsW = (tid & ~63) << 4;        // wave-uniform byte base within (buf,h,q=0)

#define STG_A(h, bsel, kt2)                                                     \
  do {                                                                          \
    const u16* _g = gA0 + (size_t)(kt2) * 64 + (size_t)(h) * 64 * ldaS;         \
    char* _l = lAc + ((bsel) << 15) + ((h) << 14) + ldsW;                       \
    gload_lds16(_g, _l);                                                        \
    gload_lds16(_g + 128 * ldaS, _l + (1 << 13));                               \
  } while (0)
#define STG_B(h, bsel, kt2)                                                     \
  do {                                                                          \
    const u16* _g = gB0 + (size_t)(kt2) * 64 + (size_t)(h) * 32 * ldbS;         \
    char* _l = lBc + ((bsel) << 15) + ((h) << 14) + ldsW;                       \
    gload_lds16(_g, _l);                                                        \
    gload_lds16(_g + 128 * ldbS, _l + (1 << 13));                               \
  } while (0)
#define BAR() __builtin_amdgcn_s_barrier()
#define LGKM0()                                                                \
  do {                                                                         \
    asm volatile("s_waitcnt lgkmcnt(0)" ::: "memory");                         \
    __builtin_amdgcn_sched_barrier(0);                                         \
  } while (0)
#define WAITV(N) asm volatile("s_waitcnt vmcnt(" #N ")" ::: "memory")

  f32x4 acc[8][4];
  const f32x4 z = {0.f, 0.f, 0.f, 0.f};
#pragma unroll
  for (int i = 0; i < 8; i++)
#pragma unroll
    for (int j = 0; j < 4; j++) acc[i][j] = z;

  short8 aq[4][2];      // current msub A-frags [fmL][kk]
  short8 bq[2][2][2];   // B-frags [nsub][fnL][kk]

  // read-address constants (bytes)
  const int aB = (wr << 13) + (fr << 7);    // rowgroup-base(wr) + fr row
  const int bB = (wc << 12) + (fr << 7);
  const int colb0 = ((qd << 4)) ^ swzx;           // kk=0
  const int colb1 = (64 + (qd << 4)) ^ swzx;      // kk=1

  // prologue: 7 half-tile stages (14 loads/thread), then wait+barrier so that
  // every wave's {A,B}[0]h0 shares are in LDS before any wave reads them.
  STG_A(0, 0, 0); STG_B(0, 0, 0); STG_A(1, 0, 0); STG_B(1, 0, 0);
  STG_A(0, 1, 1); STG_B(0, 1, 1); STG_A(1, 1, 1);
  WAITV(10);
  BAR();

  for (int kt = 0; kt < nkt; ++kt) {
    const int buf = kt & 1, nb = buf ^ 1;
    const int bo = buf << 15;
    // ---- P0: Q(msub0, nsub0); 12 ds_reads; stage B[kt+1]h1; wait {A,B}[kt]h1
#pragma unroll
    for (int fmL = 0; fmL < 4; fmL++) {
      aq[fmL][0] = ld8(lAc + bo + aB + (fmL << 11) + colb0);
      aq[fmL][1] = ld8(lAc + bo + aB + (fmL << 11) + colb1);
    }
#pragma unroll
    for (int fnL = 0; fnL < 2; fnL++) {
      bq[0][fnL][0] = ld8(lBc + bo + bB + (fnL << 11) + colb0);
      bq[0][fnL][1] = ld8(lBc + bo + bB + (fnL << 11) + colb1);
    }
    if (kt + 1 < nkt) { STG_B(1, nb, kt + 1); }
    if (kt == nkt - 1) { WAITV(0); } else { WAITV(8); }
    BAR(); LGKM0();
    mfma_q<0, 0>(acc, aq, bq);
    BAR();
    // ---- P1: Q(msub0, nsub1); 4 ds_reads; stage A[kt+2]h0
#pragma unroll
    for (int fnL = 0; fnL < 2; fnL++) {
      bq[1][fnL][0] = ld8(lBc + bo + bB + (1 << 14) + (fnL << 11) + colb0);
      bq[1][fnL][1] = ld8(lBc + bo + bB + (1 << 14) + (fnL << 11) + colb1);
    }
    if (kt + 2 < nkt) { STG_A(0, buf, kt + 2); }
    BAR(); LGKM0();
    mfma_q<0, 1>(acc, aq, bq);
    BAR();
    // ---- P2: Q(msub1, nsub1); 8 ds_reads (A msub1); stage B[kt+2]h0
#pragma unroll
    for (int fmL = 0; fmL < 4; fmL++) {
      aq[fmL][0] = ld8(lAc + bo + aB + (1 << 14) + (fmL << 11) + colb0);
      aq[fmL][1] = ld8(lAc + bo + aB + (1 << 14) + (fmL << 11) + colb1);
    }
    if (kt + 2 < nkt) { STG_B(0, buf, kt + 2); }
    BAR(); LGKM0();
    mfma_q<1, 1>(acc, aq, bq);
    BAR();
    // ---- P3: Q(msub1, nsub0); no ds_reads; stage A[kt+2]h1; wait {A,B}[kt+1]h0
    if (kt + 2 < nkt) { STG_A(1, buf, kt + 2); }
    if (kt < nkt - 2) { WAITV(10); }
    else if (kt == nkt - 2) { WAITV(4); }
    BAR(); LGKM0();
    mfma_q<1, 0>(acc, aq, bq);
    BAR();
  }

#undef STG_A
#undef STG_B
#undef BAR
#undef LGKM0
#undef WAITV

  // epilogue: full tiles, no guards
  const int mBase = m0 + wr * 128 + qd * 4;
  const int nBase = n0 + wc * 64 + fr;
#pragma unroll
  for (int fm = 0; fm < 8; fm++)
#pragma unroll
    for (int fn = 0; fn < 4; fn++)
#pragma unroll
      for (int r = 0; r < 4; r++)
        outB[(size_t)(mBase + fm * 16 + r) * ldob + nBase + fn * 16] = f2bf(acc[fm][fn][r]);
}

// ---------------- aggregation (pull, wave per node) ----------------

struct AggJob {
  const u16* H;
  const int* offs; const int* csrc; const float* cw; const float* dinv;
  const float* bias;
  float* outF; u16* outB;
  long obOff; int colOff;
};

template <int CPL>
__global__ void k_agg(AggJob j0, AggJob j1, AggJob j2, int ldh, int ldf, int ldob,
                      int relu) {
  AggJob jb = j0;
  if (blockIdx.y == 1) jb = j1;
  if (blockIdx.y == 2) jb = j2;
  int wid = blockIdx.x * (blockDim.x >> 6) + (threadIdx.x >> 6);
  if (wid >= NN) return;
  int l = threadIdx.x & 63;
  const u16* hbase = jb.H + jb.colOff + (size_t)l * CPL;
  float acc[CPL], f0[CPL], f1[CPL];
  float dv = jb.dinv[wid];
  float sw = dv * dv;
  if (CPL == 8) ld_bf16x8(hbase + (size_t)wid * ldh, f0);
  else          ld_bf16x4(hbase + (size_t)wid * ldh, f0);
#pragma unroll
  for (int j = 0; j < CPL; j++) acc[j] = f0[j] * sw;
  int e = jb.offs[wid], e1 = jb.offs[wid + 1];
  for (; e + 2 <= e1; e += 2) {
    int s0 = jb.csrc[e], s1 = jb.csrc[e + 1];
    float w0 = jb.cw[e], w1 = jb.cw[e + 1];
    if (CPL == 8) { ld_bf16x8(hbase + (size_t)s0 * ldh, f0); ld_bf16x8(hbase + (size_t)s1 * ldh, f1); }
    else          { ld_bf16x4(hbase + (size_t)s0 * ldh, f0); ld_bf16x4(hbase + (size_t)s1 * ldh, f1); }
#pragma unroll
    for (int j = 0; j < CPL; j++) acc[j] += f0[j] * w0;
#pragma unroll
    for (int j = 0; j < CPL; j++) acc[j] += f1[j] * w1;
  }
  if (e < e1) {
    int s0 = jb.csrc[e];
    float w0 = jb.cw[e];
    if (CPL == 8) ld_bf16x8(hbase + (size_t)s0 * ldh, f0);
    else          ld_bf16x4(hbase + (size_t)s0 * ldh, f0);
#pragma unroll
    for (int j = 0; j < CPL; j++) acc[j] += f0[j] * w0;
  }
  const float* bp = jb.bias + l * CPL;
#pragma unroll
  for (int j = 0; j < CPL; j++) {
    float v = acc[j] + bp[j];
    if (relu) v = v > 0.f ? v : 0.f;
    acc[j] = v;
  }
  if (jb.outF) {
    float* q = jb.outF + (size_t)wid * ldf + l * CPL;
#pragma unroll
    for (int j = 0; j < CPL; j++) q[j] = acc[j];
  }
  if (jb.outB) {
    u16* q = jb.outB + (size_t)wid * ldob + jb.obOff + l * CPL;
#pragma unroll
    for (int j = 0; j < CPL; j++) q[j] = f2bf(acc[j]);
  }
}

// ---------------- launch ----------------

extern "C" void kernel_launch(void* const* d_in, const int* in_sizes, int n_in,
                              void* d_out, int out_size, void* d_ws, size_t ws_size,
                              hipStream_t stream) {
  (void)in_sizes; (void)n_in; (void)out_size; (void)ws_size;
  const float* x_RNA = (const float*)d_in[0];
  const float* x_ADT = (const float*)d_in[1];
  EJobs ej;
  ej.ei[0] = (const int*)d_in[2]; ej.ew[0] = (const float*)d_in[3];
  ej.ei[1] = (const int*)d_in[4]; ej.ew[1] = (const float*)d_in[5];
  ej.ei[2] = (const int*)d_in[6]; ej.ew[2] = (const float*)d_in[7];
  const float* W_rna1 = (const float*)d_in[8];  const float* b_rna1 = (const float*)d_in[9];
  const float* W_rna2 = (const float*)d_in[10]; const float* b_rna2 = (const float*)d_in[11];
  const float* W_p3   = (const float*)d_in[12]; const float* b_p3   = (const float*)d_in[13];
  const float* W_sim  = (const float*)d_in[14]; const float* b_sim  = (const float*)d_in[15];
  const float* W_dist = (const float*)d_in[16]; const float* b_dist = (const float*)d_in[17];
  const float* W_f1   = (const float*)d_in[18]; const float* b_f1   = (const float*)d_in[19];
  const float* W_f2   = (const float*)d_in[20]; const float* b_f2   = (const float*)d_in[21];
  float* out = (float*)d_out;

  char* p = (char*)d_ws;
  auto alloc = [&](size_t bytes) {
    char* r = p;
    p += (bytes + 255) & ~(size_t)255;
    return r;
  };
  u16* WcT   = (u16*)alloc((size_t)1024 * KX * 2);
  u16* WsT   = (u16*)alloc((size_t)OUTC * HID * 2);
  u16* WdT   = (u16*)alloc((size_t)OUTC * HID * 2);
  u16* Wf1T  = (u16*)alloc((size_t)OUTC * HID * 2);
  u16* Wp3T  = (u16*)alloc((size_t)OUTC * KQ * 2);
  u16* WcatT = (u16*)alloc((size_t)OUTC * 768 * 2);
  float* bias2 = (float*)alloc(OUTC * 4);
  u16* ADTb = (u16*)alloc((size_t)NN * KQ * 2);
  u16* H1   = (u16*)alloc((size_t)NN * 1024 * 2);  // later: H2s|H2d|H2p
  u16* B2   = (u16*)alloc((size_t)NN * 1024 * 2);  // XS|XD, later XSDP
  float* deg = (float*)alloc((size_t)3 * NN * 4);
  int* cnt   = (int*)alloc((size_t)3 * NN * 4);
  int* offs  = (int*)alloc((size_t)3 * (NN + 1) * 4);
  int* cur   = (int*)alloc((size_t)3 * NN * 4);
  int* csrc  = (int*)alloc((size_t)3 * NE * 4);
  float* cwn = (float*)alloc((size_t)3 * NE * 4);
  int* part  = (int*)alloc(3 * 128 * 4);

  u16* Xb   = (u16*)d_out;   // bf16 x_RNA scratch: dead before first f32 output write
  u16* XS   = B2;
  u16* XD   = B2 + (size_t)NN * 512;
  u16* XSDP = B2;            // [NN, 768] = x_sim | x_dist | pro (bf16), after A2
  u16* H2s  = H1;
  u16* H2d  = H1 + (size_t)NN * 256;
  u16* H2p  = H1 + (size_t)NN * 512;

  const int T = 256;
  Prep P;
  P.xR = x_RNA; P.xA = x_ADT; P.W1 = W_rna1; P.W2 = W_rna2;
  P.Ws0 = W_sim; P.Ws1 = W_dist; P.Ws2 = W_f1; P.Ws3 = W_f2; P.Ws4 = W_p3;
  P.Wo0 = WsT; P.Wo1 = WdT; P.Wo2 = Wf1T; P.Wo3 = nullptr; P.Wo4 = Wp3T;
  P.bf1 = b_f1; P.bf2 = b_f2;
  P.Xb = Xb; P.ADTb = ADTb; P.WcT = WcT; P.WcatT = WcatT; P.bias2 = bias2;
  P.deg = deg; P.cnt = cnt; P.cur = cur;
  P.Wo3 = (u16*)(cwn);  // dead scratch until k_fill_csr3; wT5 finishes in k_prep before it
  k_prep<<<23038, T, 0, stream>>>(P);

  k_edge_count<<<dim3((NE + T - 1) / T, 3), T, 0, stream>>>(ej, deg, cnt);
  k_scan_a<<<dim3(NB79, 3), 256, 0, stream>>>(cnt, part, deg);
  k_scan_b<<<1, 128, 0, stream>>>(part);
  k_scan_c<<<dim3(NB79, 3), 256, 0, stream>>>(cnt, part, offs);
  k_fill_csr3<<<dim3((NE + T - 1) / T, 3), T, 0, stream>>>(ej, deg, offs, cur, csrc, cwn);

  GemmJob jz = {};
  // G1 main: rows [0,16384) = 64 full 256-tiles x 4 n-tiles = 256 blocks (1 round, 1 blk/CU)
  k_gemm8<<<dim3(8, 32), 512, 0, stream>>>(Xb, WcT, H1, KX, KX, 1024, KX >> 6);
  // G1 tail: rows [16384,20000) on the 128^2 kernel (29 x 8 = 232 blocks)
  GemmJob g1t = {Xb + (size_t)16384 * KX, WcT, nullptr, nullptr, H1 + (size_t)16384 * 1024,
                 KX, KX, KX};
  k_gemm<1><<<dim3(8, 29), 256, 0, stream>>>(g1t, jz, jz, NN - 16384, 0, 1024, 0, 0);
  // A1: XS = relu(agg_sim(H1[:,:512]) + b_rna1); XD likewise (dist)
  AggJob a0 = {H1, offs, csrc, cwn, deg, b_rna1, nullptr, XS, 0, 0};
  AggJob a1 = {H1, offs + (NN + 1), csrc + NE, cwn + NE, deg + NN, b_rna2, nullptr, XD, 0, 512};
  k_agg<8><<<dim3(NN / 4, 2), 256, 0, stream>>>(a0, a1, a1, 1024, 0, 512, 1);
  // G2: H2s=XS@W_sim, H2d=XD@W_dist, H2p=ADTb@W_p3
  GemmJob g2a = {XS, WsT, nullptr, nullptr, H2s, HID, HID, HID};
  GemmJob g2b = {XD, WdT, nullptr, nullptr, H2d, HID, HID, HID};
  GemmJob g2c = {ADTb, Wp3T, nullptr, nullptr, H2p, KQ, KQ, KQ};
  k_gemm<3><<<dim3(2, 157, 3), 256, 0, stream>>>(g2a, g2b, g2c, NN, 0, 256, 0, 0);
  // A2: x_sim, x_dist, pro -> f32 outputs + bf16 into XSDP
  AggJob b0 = {H2s, offs, csrc, cwn, deg, b_sim, out, XSDP, 0, 0};
  AggJob b1 = {H2d, offs + (NN + 1), csrc + NE, cwn + NE, deg + NN, b_dist,
               out + OUTSZ, XSDP, 256, 0};
  AggJob b2 = {H2p, offs + 2 * (NN + 1), csrc + 2 * NE, cwn + 2 * NE, deg + 2 * NN, b_p3,
               out + 4 * OUTSZ, XSDP, 512, 0};
  k_agg<4><<<dim3(NN / 4, 3), 256, 0, stream>>>(b0, b1, b2, 256, 256, 768, 0);
  // G5 (2 jobs): fused = XSDP[:,:512]@W_f1 + b_f1 ; fused_pro = XSDP@Wcat + bias2
  GemmJob g5a = {XSDP, Wf1T, b_f1, out + 2 * OUTSZ, nullptr, 768, 512, 512};
  GemmJob g5b = {XSDP, WcatT, bias2, out + 3 * OUTSZ, nullptr, 768, 768, 768};
  k_gemm<2><<<dim3(2, 157, 2), 256, 0, stream>>>(g5a, g5b, jz, NN, 256, 0, 0, 0);
}

// Round 5
// 819.963 us; speedup vs baseline: 1.0274x; 1.0175x over previous
//
#include <hip/hip_runtime.h>

#define AS1 __attribute__((address_space(1)))
#define AS3 __attribute__((address_space(3)))

typedef __attribute__((ext_vector_type(8))) short short8;
typedef __attribute__((ext_vector_type(4))) float f32x4;
typedef unsigned int u32;
typedef unsigned short u16;

static constexpr int NN = 20000;
static constexpr int NE = 320000;
static constexpr int INC = 2000;
static constexpr int KX = 2048;
static constexpr int HID = 512;
static constexpr int OUTC = 256;
static constexpr int QA = 100;
static constexpr int KQ = 128;
static constexpr long OUTSZ = (long)NN * OUTC;
static constexpr int NB79 = (NN + 255) / 256;   // 79
static constexpr int NREP = 8;                  // CSR atomic replicas (~1/XCD)

__device__ __forceinline__ u16 f2bf(float f) {
  u32 u = __float_as_uint(f);
  u = (u + 0x7FFFu + ((u >> 16) & 1u)) >> 16;   // RNE
  return (u16)u;
}
__device__ __forceinline__ void ld_bf16x8(const u16* p, float* f) {
  uint4 r = *(const uint4*)p;
  f[0] = __uint_as_float(r.x << 16); f[1] = __uint_as_float(r.x & 0xFFFF0000u);
  f[2] = __uint_as_float(r.y << 16); f[3] = __uint_as_float(r.y & 0xFFFF0000u);
  f[4] = __uint_as_float(r.z << 16); f[5] = __uint_as_float(r.z & 0xFFFF0000u);
  f[6] = __uint_as_float(r.w << 16); f[7] = __uint_as_float(r.w & 0xFFFF0000u);
}
__device__ __forceinline__ void ld_bf16x4(const u16* p, float* f) {
  uint2 r = *(const uint2*)p;
  f[0] = __uint_as_float(r.x << 16); f[1] = __uint_as_float(r.x & 0xFFFF0000u);
  f[2] = __uint_as_float(r.y << 16); f[3] = __uint_as_float(r.y & 0xFFFF0000u);
}

// ---------------- fused prep kernel ----------------
// Round order: latency-bound small rounds FIRST (low block IDs dispatch first and
// overlap R0's BW phase instead of forming a serial tail).
// R4 [0,769): Wcat compose + bias2 (LDS row + 8-acc MLP)
// R2 [769,1041): 5 small-weight transposes
// R3 [1041,1553): WcT LDS transpose
// R5 [1553,7178): zero degR/cntR/curR (1.44M words)
// R1 [7178,8428): x_ADT cast (16 rows/blk)
// R0 [8428,28428): x_RNA row cast->Xb (BW-dominant)
struct Prep {
  const float *xR, *xA;
  const float *W1, *W2;                     // W_rna1, W_rna2
  const float *Ws0, *Ws1, *Ws2, *Ws3, *Ws4; // W_sim, W_dist, W_f1, W_f2, W_p3
  u16 *Wo0, *Wo1, *Wo2, *Wo3, *Wo4;
  const float *bf1, *bf2;
  u16 *Xb, *ADTb, *WcT, *WcatT;
  float *bias2;
  int *zro;                                 // degR|cntR|curR contiguous
};

__global__ __launch_bounds__(256) void k_prep(Prep P) {
  int b = blockIdx.x, t = threadIdx.x;
  if (b < 769) {                         // ---- R4: Wcat compose
    int k = b, n = t;
    if (k < 512) {
      __shared__ float w2row[256];
      w2row[t] = P.Ws2[k * OUTC + t];
      __syncthreads();
      float s0 = 0.f, s1 = 0.f, s2 = 0.f, s3 = 0.f;
      float s4 = 0.f, s5 = 0.f, s6 = 0.f, s7 = 0.f;
      for (int j = 0; j < 256; j += 8) {
        s0 += w2row[j + 0] * P.Ws3[(j + 0) * OUTC + n];
        s1 += w2row[j + 1] * P.Ws3[(j + 1) * OUTC + n];
        s2 += w2row[j + 2] * P.Ws3[(j + 2) * OUTC + n];
        s3 += w2row[j + 3] * P.Ws3[(j + 3) * OUTC + n];
        s4 += w2row[j + 4] * P.Ws3[(j + 4) * OUTC + n];
        s5 += w2row[j + 5] * P.Ws3[(j + 5) * OUTC + n];
        s6 += w2row[j + 6] * P.Ws3[(j + 6) * OUTC + n];
        s7 += w2row[j + 7] * P.Ws3[(j + 7) * OUTC + n];
      }
      float s = ((s0 + s1) + (s2 + s3)) + ((s4 + s5) + (s6 + s7));
      P.WcatT[(long)n * 768 + k] = f2bf(s);
    } else if (k < 768) {
      P.WcatT[(long)n * 768 + k] = f2bf(P.Ws3[(256 + k - 512) * OUTC + n]);
    } else {
      float s0 = 0.f, s1 = 0.f, s2 = 0.f, s3 = 0.f;
      for (int j = 0; j < 256; j += 4) {
        s0 += P.bf1[j + 0] * P.Ws3[(j + 0) * OUTC + n];
        s1 += P.bf1[j + 1] * P.Ws3[(j + 1) * OUTC + n];
        s2 += P.bf1[j + 2] * P.Ws3[(j + 2) * OUTC + n];
        s3 += P.bf1[j + 3] * P.Ws3[(j + 3) * OUTC + n];
      }
      P.bias2[n] = P.bf2[n] + ((s0 + s1) + (s2 + s3));
    }
    return;
  }
  if (b < 1041) {                        // ---- R2: wT5
    int slot = (b - 769) * 256 + t;
    const float* W; u16* o; int Kin, Kpad, within;
    if (slot < 65536) {
      int j = slot >> 14; within = slot & 16383;
      W = (j == 0) ? P.Ws0 : (j == 1) ? P.Ws1 : (j == 2) ? P.Ws2 : P.Ws3;
      o = (j == 0) ? P.Wo0 : (j == 1) ? P.Wo1 : (j == 2) ? P.Wo2 : P.Wo3;
      Kin = HID; Kpad = HID;
    } else {
      within = slot - 65536; W = P.Ws4; o = P.Wo4; Kin = QA; Kpad = KQ;
    }
    int kg = Kpad >> 3;
    int n = within / kg, k8 = (within % kg) << 3;
    u16 v[8];
#pragma unroll
    for (int j = 0; j < 8; j++) {
      int k = k8 + j;
      v[j] = (k < Kin) ? f2bf(W[(long)k * OUTC + n]) : (u16)0;
    }
    *(uint4*)(o + (long)n * Kpad + k8) = *(const uint4*)v;
    return;
  }
  if (b < 1553) {                        // ---- R3: WcT transpose
    __shared__ float tile[64][65];
    int bb = b - 1041;
    int kb = (bb & 31) * 64, nb = (bb >> 5) * 64;
    const float* W = (nb < HID) ? P.W1 : P.W2;
    int nb2 = nb & (HID - 1);
#pragma unroll
    for (int p = 0; p < 4; p++) {
      int idx = p * 256 + t;
      int r = idx >> 4, c4 = (idx & 15) << 2;
      int k = kb + r;
      float4 v = {0.f, 0.f, 0.f, 0.f};
      if (k < INC) v = *(const float4*)(W + (long)k * HID + nb2 + c4);
      tile[r][c4] = v.x; tile[r][c4 + 1] = v.y; tile[r][c4 + 2] = v.z; tile[r][c4 + 3] = v.w;
    }
    __syncthreads();
#pragma unroll
    for (int p = 0; p < 2; p++) {
      int idx = p * 256 + t;
      int n = idx >> 3, kg = (idx & 7) << 3;
      u16 v[8];
#pragma unroll
      for (int j = 0; j < 8; j++) v[j] = f2bf(tile[kg + j][n]);
      *(uint4*)(P.WcT + (long)(nb + n) * KX + kb + kg) = *(const uint4*)v;
    }
    return;
  }
  if (b < 7178) {                        // ---- R5: zero degR/cntR/curR
    int i = (b - 1553) * 256 + t;
    if (i < 3 * NREP * 3 * NN) P.zro[i] = 0;
    return;
  }
  if (b < 8428) {                        // ---- R1: x_ADT cast, 16 rows/block
    int row = (b - 7178) * 16 + (t >> 4);
    int c8 = (t & 15) << 3;
    u16 v[8];
#pragma unroll
    for (int j = 0; j < 8; j++) {
      int c = c8 + j;
      v[j] = (c < QA) ? f2bf(P.xA[(long)row * QA + c]) : (u16)0;
    }
    *(uint4*)(P.ADTb + (long)row * KQ + c8) = *(const uint4*)v;
    return;
  }
  {                                      // ---- R0: x_RNA row cast
    int row = b - 8428;
    int c8 = t << 3;
    u16 v[8];
    if (c8 + 8 <= INC) {
      const float4* p = (const float4*)(P.xR + (long)row * INC + c8);
      float4 a = p[0], c = p[1];
      v[0] = f2bf(a.x); v[1] = f2bf(a.y); v[2] = f2bf(a.z); v[3] = f2bf(a.w);
      v[4] = f2bf(c.x); v[5] = f2bf(c.y); v[6] = f2bf(c.z); v[7] = f2bf(c.w);
    } else {
#pragma unroll
      for (int j = 0; j < 8; j++) {
        int c = c8 + j;
        v[j] = (c < INC) ? f2bf(P.xR[(long)row * INC + c]) : (u16)0;
      }
    }
    *(uint4*)(P.Xb + (long)row * KX + c8) = *(const uint4*)v;
  }
}

// ---------------- CSR build (8-way XCD-replica privatized atomics) ----------------
// blockIdx.x & 7 keys a replica; blocks round-robin XCDs, so each replica's lines
// stay resident in ~one L2 instead of coherence-thrashing across all 8.

struct EJobs { const int* ei[3]; const float* ew[3]; };

__global__ void k_edge_count(EJobs js, float* degR, int* cntR) {
  int g = blockIdx.y;
  int e = blockIdx.x * blockDim.x + threadIdx.x;
  if (e >= NE) return;
  int s = blockIdx.x & (NREP - 1);
  int base = (s * 3 + g) * NN;
  int dst = js.ei[g][NE + e];
  atomicAdd(&degR[base + dst], js.ew[g][e]);
  atomicAdd(&cntR[base + dst], 1);
}
// reduce replicas -> dinv, total cnt, per-replica exclusive sub-offsets; block sums.
__global__ void k_scan_a(const float* __restrict__ degR, const int* __restrict__ cntR,
                         int* __restrict__ subO, float* __restrict__ deg,
                         int* __restrict__ cnt, int* __restrict__ part) {
  __shared__ int buf[256];
  int g = blockIdx.y, b = blockIdx.x, t = threadIdx.x;
  int i = b * 256 + t;
  int v = 0;
  if (i < NN) {
    float dsum = 1.0f;                    // self loop
    int c = 0;
#pragma unroll
    for (int s = 0; s < NREP; s++) {
      int idx = (s * 3 + g) * NN + i;
      dsum += degR[idx];
      subO[idx] = c;
      c += cntR[idx];
    }
    deg[g * NN + i] = rsqrtf(dsum);
    cnt[g * NN + i] = c;
    v = c;
  }
  buf[t] = v;
  __syncthreads();
  for (int off = 128; off > 0; off >>= 1) {
    if (t < off) buf[t] += buf[t + off];
    __syncthreads();
  }
  if (t == 0) part[g * 128 + b] = buf[0];
}
__global__ void k_scan_b(int* part) {
  __shared__ int buf[128];
  int t = threadIdx.x;
  for (int g = 0; g < 3; g++) {
    int v = part[g * 128 + t];
    buf[t] = v;
    __syncthreads();
    for (int off = 1; off < 128; off <<= 1) {
      int u = (t >= off) ? buf[t - off] : 0;
      __syncthreads();
      buf[t] += u;
      __syncthreads();
    }
    part[g * 128 + t] = buf[t] - v;
    __syncthreads();
  }
}
__global__ void k_scan_c(const int* __restrict__ cnt, const int* __restrict__ part,
                         int* __restrict__ offs) {
  __shared__ int buf[256];
  int g = blockIdx.y, b = blockIdx.x, t = threadIdx.x;
  int i = b * 256 + t;
  int v = (i < NN) ? cnt[g * NN + i] : 0;
  buf[t] = v;
  __syncthreads();
  for (int off = 1; off < 256; off <<= 1) {
    int u = (t >= off) ? buf[t - off] : 0;
    __syncthreads();
    buf[t] += u;
    __syncthreads();
  }
  int base = part[g * 128 + b];
  int excl = base + buf[t] - v;
  if (i < NN) offs[g * (NN + 1) + i] = excl;
  if (i == NN - 1) offs[g * (NN + 1) + NN] = excl + v;
}
__global__ void k_fill_csr3(EJobs js, const float* __restrict__ dinv,
                            const int* __restrict__ offs, const int* __restrict__ subO,
                            int* curR, int* csrc, float* cw) {
  int g = blockIdx.y;
  int e = blockIdx.x * blockDim.x + threadIdx.x;
  if (e >= NE) return;
  int s = blockIdx.x & (NREP - 1);        // must match k_edge_count's mapping
  int sIdx = (s * 3 + g) * NN;
  int src = js.ei[g][e], d = js.ei[g][NE + e];
  float w = js.ew[g][e];
  int pos = offs[g * (NN + 1) + d] + subO[sIdx + d] + atomicAdd(&curR[sIdx + d], 1);
  csrc[g * NE + pos] = src;
  cw[g * NE + pos] = dinv[g * NN + src] * w * dinv[g * NN + d];
}

// ------- GEMM: bf16 MFMA 128x128 tile, BK=32, double-buffered LDS, 1 barrier/iter -------

__device__ __forceinline__ void gload_lds16(const void* g, void* l) {
  __builtin_amdgcn_global_load_lds((const AS1 void*)g, (AS3 void*)l, 16, 0, 0);
}

struct GemmJob {
  const u16* A; const u16* BT; const float* bias;
  float* outF; u16* outB;
  int lda, ldb, K;
};

template <int NJ>
__global__ __launch_bounds__(256) void k_gemm(GemmJob j0, GemmJob j1, GemmJob j2,
                                              int M, int ldf, int ldob, long obOff,
                                              int xcdswz) {
  GemmJob jb = j0;
  if (NJ > 1 && blockIdx.z == 1) jb = j1;
  if (NJ > 2 && blockIdx.z == 2) jb = j2;
  int m_i, n_i;
  if (xcdswz) {
    int L = blockIdx.x + (blockIdx.y << 3);
    int xcd = L & 7, j = L >> 3;
    n_i = j & 7;
    m_i = ((j >> 3) << 3) + xcd;
    if (m_i >= 157) return;
  } else {
    n_i = blockIdx.x; m_i = blockIdx.y;
  }
  const int m0 = m_i * 128, n0 = n_i * 128;

  __shared__ u16 lA[2][4096];
  __shared__ u16 lB[2][4096];
  const int tid = threadIdx.x;
  const int l = tid & 63;
  const int w = tid >> 6;
  const int wr = w >> 1, wc = w & 1;

  f32x4 acc[4][4];
  const f32x4 z = {0.f, 0.f, 0.f, 0.f};
#pragma unroll
  for (int i = 0; i < 4; i++)
#pragma unroll
    for (int j = 0; j < 4; j++) acc[i][j] = z;

  const u16* gA[2]; const u16* gB[2];
  int ldst[2];
#pragma unroll
  for (int q = 0; q < 2; q++) {
    int s = q * 256 + tid;
    int r = s >> 2, kc = s & 3;
    int ra = m0 + r; if (ra > M - 1) ra = M - 1;
    gA[q] = jb.A + (size_t)ra * jb.lda + kc * 8;
    gB[q] = jb.BT + (size_t)(n0 + r) * jb.ldb + kc * 8;
    ldst[q] = (q * 256 + w * 64) * 8;
  }

  const int fr = l & 15, qd = l >> 4;
  const int aro[4] = {(wr * 64 + 0 * 16 + fr) * 32 + qd * 8, (wr * 64 + 1 * 16 + fr) * 32 + qd * 8,
                      (wr * 64 + 2 * 16 + fr) * 32 + qd * 8, (wr * 64 + 3 * 16 + fr) * 32 + qd * 8};
  const int bro[4] = {(wc * 64 + 0 * 16 + fr) * 32 + qd * 8, (wc * 64 + 1 * 16 + fr) * 32 + qd * 8,
                      (wc * 64 + 2 * 16 + fr) * 32 + qd * 8, (wc * 64 + 3 * 16 + fr) * 32 + qd * 8};

  const int nit = jb.K >> 5;
#pragma unroll
  for (int q = 0; q < 2; q++) {
    gload_lds16(gA[q], &lA[0][0] + ldst[q]);
    gload_lds16(gB[q], &lB[0][0] + ldst[q]);
  }
  for (int i = 0; i < nit; i++) {
    __syncthreads();
    if (i + 1 < nit) {
      int nb = (i + 1) & 1, kt = (i + 1) * 32;
#pragma unroll
      for (int q = 0; q < 2; q++) {
        gload_lds16(gA[q] + kt, &lA[nb][0] + ldst[q]);
        gload_lds16(gB[q] + kt, &lB[nb][0] + ldst[q]);
      }
    }
    const u16* la = &lA[i & 1][0];
    const u16* lb = &lB[i & 1][0];
    short8 af[4], bf[4];
#pragma unroll
    for (int t = 0; t < 4; t++) {
      af[t] = *(const short8*)(la + aro[t]);
      bf[t] = *(const short8*)(lb + bro[t]);
    }
#pragma unroll
    for (int i2 = 0; i2 < 4; i2++)
#pragma unroll
      for (int j = 0; j < 4; j++)
        acc[i2][j] = __builtin_amdgcn_mfma_f32_16x16x32_bf16(af[i2], bf[j], acc[i2][j], 0, 0, 0);
  }

#pragma unroll
  for (int i = 0; i < 4; i++) {
#pragma unroll
    for (int r = 0; r < 4; r++) {
      int m = m0 + wr * 64 + i * 16 + qd * 4 + r;
      if (m < M) {
#pragma unroll
        for (int j = 0; j < 4; j++) {
          int n = n0 + wc * 64 + j * 16 + fr;
          float v = acc[i][j][r];
          if (jb.bias) v += jb.bias[n];
          if (jb.outF) jb.outF[(size_t)m * ldf + n] = v;
          if (jb.outB) jb.outB[(size_t)m * ldob + obOff + n] = f2bf(v);
        }
      }
    }
  }
}

// ------- GEMM8: 256x256 tile, BK=64, 8-wave, 4-phase/K-tile counted-vmcnt pipeline -------
// Waits: pre-loop WAITV(10)+BAR -> {A,B}[0]h0 visible to all waves at P0.
//   kt.P0: stage, WAITV(8)  (last tile: 0), BAR  -> {A,B}[kt]h1 visible at P1/P2.
//   kt.P3: stage, WAITV(10) (kt==nkt-2: 4), BAR  -> {A,B}[kt+1]h0 visible at next P0.

template <int MS, int NS>
__device__ __forceinline__ void mfma_q(f32x4 (&acc)[8][4], const short8 (&aq)[4][2],
                                       const short8 (&bq)[2][2][2]) {
  __builtin_amdgcn_s_setprio(1);
#pragma unroll
  for (int fm = 0; fm < 4; fm++)
#pragma unroll
    for (int fn = 0; fn < 2; fn++)
#pragma unroll
      for (int kk = 0; kk < 2; kk++)
        acc[MS * 4 + fm][NS * 2 + fn] = __builtin_amdgcn_mfma_f32_16x16x32_bf16(
            aq[fm][kk], bq[NS][fn][kk], acc[MS * 4 + fm][NS * 2 + fn], 0, 0, 0);
  __builtin_amdgcn_s_setprio(0);
}

__device__ __forceinline__ short8 ld8(const char* p) { return *(const short8*)p; }

__global__ __launch_bounds__(512, 2) void k_gemm8(const u16* __restrict__ A,
                                                  const u16* __restrict__ BT,
                                                  u16* __restrict__ outB,
                                                  int lda, int ldb, int ldob, int nkt) {
  __shared__ u16 lA[2][16384];   // 64KB
  __shared__ u16 lB[2][16384];   // 64KB
  const int m_i = (blockIdx.x << 3) + (blockIdx.y >> 2);
  const int n_i = blockIdx.y & 3;
  const int m0 = m_i * 256, n0 = n_i * 256;
  const int tid = threadIdx.x;
  const int l = tid & 63, w = tid >> 6;
  const int wr = w >> 2, wc = w & 3;        // 2 x 4 waves; wave tile 128 x 64
  const int fr = l & 15, qd = l >> 4;
  const int swzx = (fr & 7) << 4;           // read-side byte XOR

  char* lAc = (char*)&lA[0][0];
  char* lBc = (char*)&lB[0][0];

  const size_t ldaS = (size_t)lda, ldbS = (size_t)ldb;
  const int lr = tid >> 3;
  const int cl = (tid & 7) ^ (lr & 7);
  const u16* gA0 = A + (size_t)(m0 + lr) * ldaS + cl * 8;
  const u16* gB0 = BT + (size_t)(n0 + ((lr >> 5) << 6) + (lr & 31)) * ldbS + cl * 8;
  const int ldsW = (tid & ~63) << 4;        // wave-uniform byte base within (buf,h,q=0)

#define STG_A(h, bsel, kt2)                                                     \
  do {                                                                          \
    const u16* _g = gA0 + (size_t)(kt2) * 64 + (size_t)(h) * 64 * ldaS;         \
    char* _l = lAc + ((bsel) << 15) + ((h) << 14) + ldsW;                       \
    gload_lds16(_g, _l);                                                        \
    gload_lds16(_g + 128 * ldaS, _l + (1 << 13));                               \
  } while (0)
#define STG_B(h, bsel, kt2)                                                     \
  do {                                                                          \
    const u16* _g = gB0 + (size_t)(kt2) * 64 + (size_t)(h) * 32 * ldbS;         \
    char* _l = lBc + ((bsel) << 15) + ((h) << 14) + ldsW;                       \
    gload_lds16(_g, _l);                                                        \
    gload_lds16(_g + 128 * ldbS, _l + (1 << 13));                               \
  } while (0)
#define BAR() __builtin_amdgcn_s_barrier()
#define LGKM0()                                                                \
  do {                                                                         \
    asm volatile("s_waitcnt lgkmcnt(0)" ::: "memory");                         \
    __builtin_amdgcn_sched_barrier(0);                                         \
  } while (0)
#define WAITV(N) asm volatile("s_waitcnt vmcnt(" #N ")" ::: "memory")

  f32x4 acc[8][4];
  const f32x4 z = {0.f, 0.f, 0.f, 0.f};
#pragma unroll
  for (int i = 0; i < 8; i++)
#pragma unroll
    for (int j = 0; j < 4; j++) acc[i][j] = z;

  short8 aq[4][2];      // current msub A-frags [fmL][kk]
  short8 bq[2][2][2];   // B-frags [nsub][fnL][kk]

  const int aB = (wr << 13) + (fr << 7);    // rowgroup-base(wr) + fr row
  const int bB = (wc << 12) + (fr << 7);
  const int colb0 = ((qd << 4)) ^ swzx;           // kk=0
  const int colb1 = (64 + (qd << 4)) ^ swzx;      // kk=1

  STG_A(0, 0, 0); STG_B(0, 0, 0); STG_A(1, 0, 0); STG_B(1, 0, 0);
  STG_A(0, 1, 1); STG_B(0, 1, 1); STG_A(1, 1, 1);
  WAITV(10);
  BAR();

  for (int kt = 0; kt < nkt; ++kt) {
    const int buf = kt & 1, nb = buf ^ 1;
    const int bo = buf << 15;
    // ---- P0: Q(msub0, nsub0); 12 ds_reads; stage B[kt+1]h1; wait {A,B}[kt]h1
#pragma unroll
    for (int fmL = 0; fmL < 4; fmL++) {
      aq[fmL][0] = ld8(lAc + bo + aB + (fmL << 11) + colb0);
      aq[fmL][1] = ld8(lAc + bo + aB + (fmL << 11) + colb1);
    }
#pragma unroll
    for (int fnL = 0; fnL < 2; fnL++) {
      bq[0][fnL][0] = ld8(lBc + bo + bB + (fnL << 11) + colb0);
      bq[0][fnL][1] = ld8(lBc + bo + bB + (fnL << 11) + colb1);
    }
    if (kt + 1 < nkt) { STG_B(1, nb, kt + 1); }
    if (kt == nkt - 1) { WAITV(0); } else { WAITV(8); }
    BAR(); LGKM0();
    mfma_q<0, 0>(acc, aq, bq);
    BAR();
    // ---- P1: Q(msub0, nsub1); 4 ds_reads; stage A[kt+2]h0
#pragma unroll
    for (int fnL = 0; fnL < 2; fnL++) {
      bq[1][fnL][0] = ld8(lBc + bo + bB + (1 << 14) + (fnL << 11) + colb0);
      bq[1][fnL][1] = ld8(lBc + bo + bB + (1 << 14) + (fnL << 11) + colb1);
    }
    if (kt + 2 < nkt) { STG_A(0, buf, kt + 2); }
    BAR(); LGKM0();
    mfma_q<0, 1>(acc, aq, bq);
    BAR();
    // ---- P2: Q(msub1, nsub1); 8 ds_reads (A msub1); stage B[kt+2]h0
#pragma unroll
    for (int fmL = 0; fmL < 4; fmL++) {
      aq[fmL][0] = ld8(lAc + bo + aB + (1 << 14) + (fmL << 11) + colb0);
      aq[fmL][1] = ld8(lAc + bo + aB + (1 << 14) + (fmL << 11) + colb1);
    }
    if (kt + 2 < nkt) { STG_B(0, buf, kt + 2); }
    BAR(); LGKM0();
    mfma_q<1, 1>(acc, aq, bq);
    BAR();
    // ---- P3: Q(msub1, nsub0); no ds_reads; stage A[kt+2]h1; wait {A,B}[kt+1]h0
    if (kt + 2 < nkt) { STG_A(1, buf, kt + 2); }
    if (kt < nkt - 2) { WAITV(10); }
    else if (kt == nkt - 2) { WAITV(4); }
    BAR(); LGKM0();
    mfma_q<1, 0>(acc, aq, bq);
    BAR();
  }

#undef STG_A
#undef STG_B
#undef BAR
#undef LGKM0
#undef WAITV

  const int mBase = m0 + wr * 128 + qd * 4;
  const int nBase = n0 + wc * 64 + fr;
#pragma unroll
  for (int fm = 0; fm < 8; fm++)
#pragma unroll
    for (int fn = 0; fn < 4; fn++)
#pragma unroll
      for (int r = 0; r < 4; r++)
        outB[(size_t)(mBase + fm * 16 + r) * ldob + nBase + fn * 16] = f2bf(acc[fm][fn][r]);
}

// ---------------- aggregation (pull, wave per node) ----------------

struct AggJob {
  const u16* H;
  const int* offs; const int* csrc; const float* cw; const float* dinv;
  const float* bias;
  float* outF; u16* outB;
  long obOff; int colOff;
};

template <int CPL>
__global__ void k_agg(AggJob j0, AggJob j1, AggJob j2, int ldh, int ldf, int ldob,
                      int relu) {
  AggJob jb = j0;
  if (blockIdx.y == 1) jb = j1;
  if (blockIdx.y == 2) jb = j2;
  int wid = blockIdx.x * (blockDim.x >> 6) + (threadIdx.x >> 6);
  if (wid >= NN) return;
  int l = threadIdx.x & 63;
  const u16* hbase = jb.H + jb.colOff + (size_t)l * CPL;
  float acc[CPL], f0[CPL], f1[CPL];
  float dv = jb.dinv[wid];
  float sw = dv * dv;
  if (CPL == 8) ld_bf16x8(hbase + (size_t)wid * ldh, f0);
  else          ld_bf16x4(hbase + (size_t)wid * ldh, f0);
#pragma unroll
  for (int j = 0; j < CPL; j++) acc[j] = f0[j] * sw;
  int e = jb.offs[wid], e1 = jb.offs[wid + 1];
  for (; e + 2 <= e1; e += 2) {
    int s0 = jb.csrc[e], s1 = jb.csrc[e + 1];
    float w0 = jb.cw[e], w1 = jb.cw[e + 1];
    if (CPL == 8) { ld_bf16x8(hbase + (size_t)s0 * ldh, f0); ld_bf16x8(hbase + (size_t)s1 * ldh, f1); }
    else          { ld_bf16x4(hbase + (size_t)s0 * ldh, f0); ld_bf16x4(hbase + (size_t)s1 * ldh, f1); }
#pragma unroll
    for (int j = 0; j < CPL; j++) acc[j] += f0[j] * w0;
#pragma unroll
    for (int j = 0; j < CPL; j++) acc[j] += f1[j] * w1;
  }
  if (e < e1) {
    int s0 = jb.csrc[e];
    float w0 = jb.cw[e];
    if (CPL == 8) ld_bf16x8(hbase + (size_t)s0 * ldh, f0);
    else          ld_bf16x4(hbase + (size_t)s0 * ldh, f0);
#pragma unroll
    for (int j = 0; j < CPL; j++) acc[j] += f0[j] * w0;
  }
  const float* bp = jb.bias + l * CPL;
#pragma unroll
  for (int j = 0; j < CPL; j++) {
    float v = acc[j] + bp[j];
    if (relu) v = v > 0.f ? v : 0.f;
    acc[j] = v;
  }
  if (jb.outF) {
    float* q = jb.outF + (size_t)wid * ldf + l * CPL;
#pragma unroll
    for (int j = 0; j < CPL; j++) q[j] = acc[j];
  }
  if (jb.outB) {
    u16* q = jb.outB + (size_t)wid * ldob + jb.obOff + l * CPL;
#pragma unroll
    for (int j = 0; j < CPL; j++) q[j] = f2bf(acc[j]);
  }
}

// ---------------- launch ----------------

extern "C" void kernel_launch(void* const* d_in, const int* in_sizes, int n_in,
                              void* d_out, int out_size, void* d_ws, size_t ws_size,
                              hipStream_t stream) {
  (void)in_sizes; (void)n_in; (void)out_size; (void)ws_size;
  const float* x_RNA = (const float*)d_in[0];
  const float* x_ADT = (const float*)d_in[1];
  EJobs ej;
  ej.ei[0] = (const int*)d_in[2]; ej.ew[0] = (const float*)d_in[3];
  ej.ei[1] = (const int*)d_in[4]; ej.ew[1] = (const float*)d_in[5];
  ej.ei[2] = (const int*)d_in[6]; ej.ew[2] = (const float*)d_in[7];
  const float* W_rna1 = (const float*)d_in[8];  const float* b_rna1 = (const float*)d_in[9];
  const float* W_rna2 = (const float*)d_in[10]; const float* b_rna2 = (const float*)d_in[11];
  const float* W_p3   = (const float*)d_in[12]; const float* b_p3   = (const float*)d_in[13];
  const float* W_sim  = (const float*)d_in[14]; const float* b_sim  = (const float*)d_in[15];
  const float* W_dist = (const float*)d_in[16]; const float* b_dist = (const float*)d_in[17];
  const float* W_f1   = (const float*)d_in[18]; const float* b_f1   = (const float*)d_in[19];
  const float* W_f2   = (const float*)d_in[20]; const float* b_f2   = (const float*)d_in[21];
  float* out = (float*)d_out;

  char* p = (char*)d_ws;
  auto alloc = [&](size_t bytes) {
    char* r = p;
    p += (bytes + 255) & ~(size_t)255;
    return r;
  };
  u16* WcT   = (u16*)alloc((size_t)1024 * KX * 2);
  u16* WsT   = (u16*)alloc((size_t)OUTC * HID * 2);
  u16* WdT   = (u16*)alloc((size_t)OUTC * HID * 2);
  u16* Wf1T  = (u16*)alloc((size_t)OUTC * HID * 2);
  u16* Wp3T  = (u16*)alloc((size_t)OUTC * KQ * 2);
  u16* WcatT = (u16*)alloc((size_t)OUTC * 768 * 2);
  float* bias2 = (float*)alloc(OUTC * 4);
  u16* ADTb = (u16*)alloc((size_t)NN * KQ * 2);
  u16* H1   = (u16*)alloc((size_t)NN * 1024 * 2);  // later: H2s|H2d|H2p
  u16* B2   = (u16*)alloc((size_t)NN * 1024 * 2);  // XS|XD, later XSDP
  float* deg = (float*)alloc((size_t)3 * NN * 4);
  int* cnt   = (int*)alloc((size_t)3 * NN * 4);
  int* offs  = (int*)alloc((size_t)3 * (NN + 1) * 4);
  int* csrc  = (int*)alloc((size_t)3 * NE * 4);
  float* cwn = (float*)alloc((size_t)3 * NE * 4);
  int* part  = (int*)alloc(3 * 128 * 4);

  u16* Xb   = (u16*)d_out;   // bf16 x_RNA scratch: dead before first f32 output write
  u16* XS   = B2;
  u16* XD   = B2 + (size_t)NN * 512;
  u16* XSDP = B2;            // [NN, 768] = x_sim | x_dist | pro (bf16), after A2
  u16* H2s  = H1;
  u16* H2d  = H1 + (size_t)NN * 256;
  u16* H2p  = H1 + (size_t)NN * 512;

  // CSR replica state carved from B2 (B2 is dead until A1, which runs after fill):
  // degR | cntR | curR (contiguous, zeroed by prep R5) then subO (written by scan_a)
  int* wsCsr  = (int*)B2;
  float* degR = (float*)wsCsr;                  // [NREP][3][NN]
  int*   cntR = wsCsr + NREP * 3 * NN;
  int*   curR = wsCsr + 2 * NREP * 3 * NN;
  int*   subO = wsCsr + 3 * NREP * 3 * NN;

  const int T = 256;
  Prep P;
  P.xR = x_RNA; P.xA = x_ADT; P.W1 = W_rna1; P.W2 = W_rna2;
  P.Ws0 = W_sim; P.Ws1 = W_dist; P.Ws2 = W_f1; P.Ws3 = W_f2; P.Ws4 = W_p3;
  P.Wo0 = WsT; P.Wo1 = WdT; P.Wo2 = Wf1T; P.Wo3 = nullptr; P.Wo4 = Wp3T;
  P.bf1 = b_f1; P.bf2 = b_f2;
  P.Xb = Xb; P.ADTb = ADTb; P.WcT = WcT; P.WcatT = WcatT; P.bias2 = bias2;
  P.zro = wsCsr;
  P.Wo3 = (u16*)(cwn);  // dead scratch until k_fill_csr3; wT5 finishes in k_prep before it
  k_prep<<<28428, T, 0, stream>>>(P);

  k_edge_count<<<dim3((NE + T - 1) / T, 3), T, 0, stream>>>(ej, degR, cntR);
  k_scan_a<<<dim3(NB79, 3), 256, 0, stream>>>(degR, cntR, subO, deg, cnt, part);
  k_scan_b<<<1, 128, 0, stream>>>(part);
  k_scan_c<<<dim3(NB79, 3), 256, 0, stream>>>(cnt, part, offs);
  k_fill_csr3<<<dim3((NE + T - 1) / T, 3), T, 0, stream>>>(ej, deg, offs, subO, curR, csrc, cwn);

  GemmJob jz = {};
  // G1 main: rows [0,16384) = 64 full 256-tiles x 4 n-tiles = 256 blocks (1 round, 1 blk/CU)
  k_gemm8<<<dim3(8, 32), 512, 0, stream>>>(Xb, WcT, H1, KX, KX, 1024, KX >> 6);
  // G1 tail: rows [16384,20000) on the 128^2 kernel (29 x 8 = 232 blocks)
  GemmJob g1t = {Xb + (size_t)16384 * KX, WcT, nullptr, nullptr, H1 + (size_t)16384 * 1024,
                 KX, KX, KX};
  k_gemm<1><<<dim3(8, 29), 256, 0, stream>>>(g1t, jz, jz, NN - 16384, 0, 1024, 0, 0);
  // A1: XS = relu(agg_sim(H1[:,:512]) + b_rna1); XD likewise (dist)
  AggJob a0 = {H1, offs, csrc, cwn, deg, b_rna1, nullptr, XS, 0, 0};
  AggJob a1 = {H1, offs + (NN + 1), csrc + NE, cwn + NE, deg + NN, b_rna2, nullptr, XD, 0, 512};
  k_agg<8><<<dim3(NN / 4, 2), 256, 0, stream>>>(a0, a1, a1, 1024, 0, 512, 1);
  // G2: H2s=XS@W_sim, H2d=XD@W_dist, H2p=ADTb@W_p3
  GemmJob g2a = {XS, WsT, nullptr, nullptr, H2s, HID, HID, HID};
  GemmJob g2b = {XD, WdT, nullptr, nullptr, H2d, HID, HID, HID};
  GemmJob g2c = {ADTb, Wp3T, nullptr, nullptr, H2p, KQ, KQ, KQ};
  k_gemm<3><<<dim3(2, 157, 3), 256, 0, stream>>>(g2a, g2b, g2c, NN, 0, 256, 0, 0);
  // A2: x_sim, x_dist, pro -> f32 outputs + bf16 into XSDP
  AggJob b0 = {H2s, offs, csrc, cwn, deg, b_sim, out, XSDP, 0, 0};
  AggJob b1 = {H2d, offs + (NN + 1), csrc + NE, cwn + NE, deg + NN, b_dist,
               out + OUTSZ, XSDP, 256, 0};
  AggJob b2 = {H2p, offs + 2 * (NN + 1), csrc + 2 * NE, cwn + 2 * NE, deg + 2 * NN, b_p3,
               out + 4 * OUTSZ, XSDP, 512, 0};
  k_agg<4><<<dim3(NN / 4, 3), 256, 0, stream>>>(b0, b1, b2, 256, 256, 768, 0);
  // G5 (2 jobs): fused = XSDP[:,:512]@W_f1 + b_f1 ; fused_pro = XSDP@Wcat + bias2
  GemmJob g5a = {XSDP, Wf1T, b_f1, out + 2 * OUTSZ, nullptr, 768, 512, 512};
  GemmJob g5b = {XSDP, WcatT, bias2, out + 3 * OUTSZ, nullptr, 768, 768, 768};
  k_gemm<2><<<dim3(2, 157, 2), 256, 0, stream>>>(g5a, g5b, jz, NN, 256, 0, 0, 0);
}

// Round 6
// 800.357 us; speedup vs baseline: 1.0526x; 1.0245x over previous
//
#include <hip/hip_runtime.h>

#define AS1 __attribute__((address_space(1)))
#define AS3 __attribute__((address_space(3)))

typedef __attribute__((ext_vector_type(8))) short short8;
typedef __attribute__((ext_vector_type(4))) float f32x4;
typedef unsigned int u32;
typedef unsigned short u16;

static constexpr int NN = 20000;
static constexpr int NE = 320000;
static constexpr int INC = 2000;
static constexpr int KX = 2048;
static constexpr int HID = 512;
static constexpr int OUTC = 256;
static constexpr int QA = 100;
static constexpr int KQ = 128;
static constexpr long OUTSZ = (long)NN * OUTC;
static constexpr int NB79 = (NN + 255) / 256;   // 79
static constexpr int NREP = 8;                  // CSR atomic replicas (~1/XCD)

__device__ __forceinline__ u16 f2bf(float f) {
  u32 u = __float_as_uint(f);
  u = (u + 0x7FFFu + ((u >> 16) & 1u)) >> 16;   // RNE
  return (u16)u;
}
__device__ __forceinline__ void ld_bf16x8(const u16* p, float* f) {
  uint4 r = *(const uint4*)p;
  f[0] = __uint_as_float(r.x << 16); f[1] = __uint_as_float(r.x & 0xFFFF0000u);
  f[2] = __uint_as_float(r.y << 16); f[3] = __uint_as_float(r.y & 0xFFFF0000u);
  f[4] = __uint_as_float(r.z << 16); f[5] = __uint_as_float(r.z & 0xFFFF0000u);
  f[6] = __uint_as_float(r.w << 16); f[7] = __uint_as_float(r.w & 0xFFFF0000u);
}
__device__ __forceinline__ void ld_bf16x4(const u16* p, float* f) {
  uint2 r = *(const uint2*)p;
  f[0] = __uint_as_float(r.x << 16); f[1] = __uint_as_float(r.x & 0xFFFF0000u);
  f[2] = __uint_as_float(r.y << 16); f[3] = __uint_as_float(r.y & 0xFFFF0000u);
}

struct EJobs { const int* ei[3]; const float* ew[3]; };

// ---------------- zero replica state (must precede k_prep's EC round) ----------------
__global__ __launch_bounds__(256) void k_zero(uint4* z) {
  int i = blockIdx.x * 256 + threadIdx.x;
  if (i < (3 * NREP * 3 * NN) / 4) z[i] = uint4{0, 0, 0, 0};
}

// ---------------- fused prep kernel ----------------
// Latency-bound rounds first (overlap R0's BW phase instead of serial tail).
// R4 [0,769): Wcat compose + bias2 (LDS row + 8-acc MLP)
// R2 [769,1041): 5 small-weight transposes
// R3 [1041,1553): WcT LDS transpose
// EC [1553,5303): edge count, replicated atomics (independent of all other rounds;
//                 replica state zeroed by k_zero BEFORE this kernel)
// R1 [5303,6553): x_ADT cast (16 rows/blk)
// R0 [6553,26553): x_RNA row cast->Xb (BW-dominant)
struct Prep {
  const float *xR, *xA;
  const float *W1, *W2;                     // W_rna1, W_rna2
  const float *Ws0, *Ws1, *Ws2, *Ws3, *Ws4; // W_sim, W_dist, W_f1, W_f2, W_p3
  u16 *Wo0, *Wo1, *Wo2, *Wo3, *Wo4;
  const float *bf1, *bf2;
  u16 *Xb, *ADTb, *WcT, *WcatT;
  float *bias2;
  EJobs ej; float* degR; int* cntR;
};

__global__ __launch_bounds__(256) void k_prep(Prep P) {
  int b = blockIdx.x, t = threadIdx.x;
  if (b < 769) {                         // ---- R4: Wcat compose
    int k = b, n = t;
    if (k < 512) {
      __shared__ float w2row[256];
      w2row[t] = P.Ws2[k * OUTC + t];
      __syncthreads();
      float s0 = 0.f, s1 = 0.f, s2 = 0.f, s3 = 0.f;
      float s4 = 0.f, s5 = 0.f, s6 = 0.f, s7 = 0.f;
      for (int j = 0; j < 256; j += 8) {
        s0 += w2row[j + 0] * P.Ws3[(j + 0) * OUTC + n];
        s1 += w2row[j + 1] * P.Ws3[(j + 1) * OUTC + n];
        s2 += w2row[j + 2] * P.Ws3[(j + 2) * OUTC + n];
        s3 += w2row[j + 3] * P.Ws3[(j + 3) * OUTC + n];
        s4 += w2row[j + 4] * P.Ws3[(j + 4) * OUTC + n];
        s5 += w2row[j + 5] * P.Ws3[(j + 5) * OUTC + n];
        s6 += w2row[j + 6] * P.Ws3[(j + 6) * OUTC + n];
        s7 += w2row[j + 7] * P.Ws3[(j + 7) * OUTC + n];
      }
      float s = ((s0 + s1) + (s2 + s3)) + ((s4 + s5) + (s6 + s7));
      P.WcatT[(long)n * 768 + k] = f2bf(s);
    } else if (k < 768) {
      P.WcatT[(long)n * 768 + k] = f2bf(P.Ws3[(256 + k - 512) * OUTC + n]);
    } else {
      float s0 = 0.f, s1 = 0.f, s2 = 0.f, s3 = 0.f;
      for (int j = 0; j < 256; j += 4) {
        s0 += P.bf1[j + 0] * P.Ws3[(j + 0) * OUTC + n];
        s1 += P.bf1[j + 1] * P.Ws3[(j + 1) * OUTC + n];
        s2 += P.bf1[j + 2] * P.Ws3[(j + 2) * OUTC + n];
        s3 += P.bf1[j + 3] * P.Ws3[(j + 3) * OUTC + n];
      }
      P.bias2[n] = P.bf2[n] + ((s0 + s1) + (s2 + s3));
    }
    return;
  }
  if (b < 1041) {                        // ---- R2: wT5
    int slot = (b - 769) * 256 + t;
    const float* W; u16* o; int Kin, Kpad, within;
    if (slot < 65536) {
      int j = slot >> 14; within = slot & 16383;
      W = (j == 0) ? P.Ws0 : (j == 1) ? P.Ws1 : (j == 2) ? P.Ws2 : P.Ws3;
      o = (j == 0) ? P.Wo0 : (j == 1) ? P.Wo1 : (j == 2) ? P.Wo2 : P.Wo3;
      Kin = HID; Kpad = HID;
    } else {
      within = slot - 65536; W = P.Ws4; o = P.Wo4; Kin = QA; Kpad = KQ;
    }
    int kg = Kpad >> 3;
    int n = within / kg, k8 = (within % kg) << 3;
    u16 v[8];
#pragma unroll
    for (int j = 0; j < 8; j++) {
      int k = k8 + j;
      v[j] = (k < Kin) ? f2bf(W[(long)k * OUTC + n]) : (u16)0;
    }
    *(uint4*)(o + (long)n * Kpad + k8) = *(const uint4*)v;
    return;
  }
  if (b < 1553) {                        // ---- R3: WcT transpose
    __shared__ float tile[64][65];
    int bb = b - 1041;
    int kb = (bb & 31) * 64, nb = (bb >> 5) * 64;
    const float* W = (nb < HID) ? P.W1 : P.W2;
    int nb2 = nb & (HID - 1);
#pragma unroll
    for (int p = 0; p < 4; p++) {
      int idx = p * 256 + t;
      int r = idx >> 4, c4 = (idx & 15) << 2;
      int k = kb + r;
      float4 v = {0.f, 0.f, 0.f, 0.f};
      if (k < INC) v = *(const float4*)(W + (long)k * HID + nb2 + c4);
      tile[r][c4] = v.x; tile[r][c4 + 1] = v.y; tile[r][c4 + 2] = v.z; tile[r][c4 + 3] = v.w;
    }
    __syncthreads();
#pragma unroll
    for (int p = 0; p < 2; p++) {
      int idx = p * 256 + t;
      int n = idx >> 3, kg = (idx & 7) << 3;
      u16 v[8];
#pragma unroll
      for (int j = 0; j < 8; j++) v[j] = f2bf(tile[kg + j][n]);
      *(uint4*)(P.WcT + (long)(nb + n) * KX + kb + kg) = *(const uint4*)v;
    }
    return;
  }
  if (b < 5303) {                        // ---- EC: edge count (replicated atomics)
    int idx = b - 1553;
    int g = idx / 1250, eb = idx - g * 1250;   // eb in [0,1250)
    int e = eb * 256 + t;                      // 1250*256 == NE exactly
    int s = eb & (NREP - 1);                   // must match k_fill_csr3's mapping
    int base = (s * 3 + g) * NN;
    int dst = P.ej.ei[g][NE + e];
    atomicAdd(&P.degR[base + dst], P.ej.ew[g][e]);
    atomicAdd(&P.cntR[base + dst], 1);
    return;
  }
  if (b < 6553) {                        // ---- R1: x_ADT cast, 16 rows/block
    int row = (b - 5303) * 16 + (t >> 4);
    int c8 = (t & 15) << 3;
    u16 v[8];
#pragma unroll
    for (int j = 0; j < 8; j++) {
      int c = c8 + j;
      v[j] = (c < QA) ? f2bf(P.xA[(long)row * QA + c]) : (u16)0;
    }
    *(uint4*)(P.ADTb + (long)row * KQ + c8) = *(const uint4*)v;
    return;
  }
  {                                      // ---- R0: x_RNA row cast
    int row = b - 6553;
    int c8 = t << 3;
    u16 v[8];
    if (c8 + 8 <= INC) {
      const float4* p = (const float4*)(P.xR + (long)row * INC + c8);
      float4 a = p[0], c = p[1];
      v[0] = f2bf(a.x); v[1] = f2bf(a.y); v[2] = f2bf(a.z); v[3] = f2bf(a.w);
      v[4] = f2bf(c.x); v[5] = f2bf(c.y); v[6] = f2bf(c.z); v[7] = f2bf(c.w);
    } else {
#pragma unroll
      for (int j = 0; j < 8; j++) {
        int c = c8 + j;
        v[j] = (c < INC) ? f2bf(P.xR[(long)row * INC + c]) : (u16)0;
      }
    }
    *(uint4*)(P.Xb + (long)row * KX + c8) = *(const uint4*)v;
  }
}

// ---------------- CSR build (8-way XCD-replica privatized atomics) ----------------

// reduce replicas -> dinv, total cnt, per-replica exclusive sub-offsets; block sums.
__global__ void k_scan_a(const float* __restrict__ degR, const int* __restrict__ cntR,
                         int* __restrict__ subO, float* __restrict__ deg,
                         int* __restrict__ cnt, int* __restrict__ part) {
  __shared__ int buf[256];
  int g = blockIdx.y, b = blockIdx.x, t = threadIdx.x;
  int i = b * 256 + t;
  int v = 0;
  if (i < NN) {
    float dsum = 1.0f;                    // self loop
    int c = 0;
#pragma unroll
    for (int s = 0; s < NREP; s++) {
      int idx = (s * 3 + g) * NN + i;
      dsum += degR[idx];
      subO[idx] = c;
      c += cntR[idx];
    }
    deg[g * NN + i] = rsqrtf(dsum);
    cnt[g * NN + i] = c;
    v = c;
  }
  buf[t] = v;
  __syncthreads();
  for (int off = 128; off > 0; off >>= 1) {
    if (t < off) buf[t] += buf[t + off];
    __syncthreads();
  }
  if (t == 0) part[g * 128 + b] = buf[0];
}
__global__ void k_scan_b(int* part) {
  __shared__ int buf[128];
  int t = threadIdx.x;
  for (int g = 0; g < 3; g++) {
    int v = part[g * 128 + t];
    buf[t] = v;
    __syncthreads();
    for (int off = 1; off < 128; off <<= 1) {
      int u = (t >= off) ? buf[t - off] : 0;
      __syncthreads();
      buf[t] += u;
      __syncthreads();
    }
    part[g * 128 + t] = buf[t] - v;
    __syncthreads();
  }
}
__global__ void k_scan_c(const int* __restrict__ cnt, const int* __restrict__ part,
                         int* __restrict__ offs) {
  __shared__ int buf[256];
  int g = blockIdx.y, b = blockIdx.x, t = threadIdx.x;
  int i = b * 256 + t;
  int v = (i < NN) ? cnt[g * NN + i] : 0;
  buf[t] = v;
  __syncthreads();
  for (int off = 1; off < 256; off <<= 1) {
    int u = (t >= off) ? buf[t - off] : 0;
    __syncthreads();
    buf[t] += u;
    __syncthreads();
  }
  int base = part[g * 128 + b];
  int excl = base + buf[t] - v;
  if (i < NN) offs[g * (NN + 1) + i] = excl;
  if (i == NN - 1) offs[g * (NN + 1) + NN] = excl + v;
}
__global__ void k_fill_csr3(EJobs js, const float* __restrict__ dinv,
                            const int* __restrict__ offs, const int* __restrict__ subO,
                            int* curR, int* csrc, float* cw) {
  int g = blockIdx.y;
  int e = blockIdx.x * blockDim.x + threadIdx.x;
  if (e >= NE) return;
  int s = blockIdx.x & (NREP - 1);        // must match prep EC's mapping
  int sIdx = (s * 3 + g) * NN;
  int src = js.ei[g][e], d = js.ei[g][NE + e];
  float w = js.ew[g][e];
  int pos = offs[g * (NN + 1) + d] + subO[sIdx + d] + atomicAdd(&curR[sIdx + d], 1);
  csrc[g * NE + pos] = src;
  cw[g * NE + pos] = dinv[g * NN + src] * w * dinv[g * NN + d];
}

// ------- GEMM: bf16 MFMA 128x128 tile, BK=32, double-buffered LDS, 1 barrier/iter -------

__device__ __forceinline__ void gload_lds16(const void* g, void* l) {
  __builtin_amdgcn_global_load_lds((const AS1 void*)g, (AS3 void*)l, 16, 0, 0);
}

struct GemmJob {
  const u16* A; const u16* BT; const float* bias;
  float* outF; u16* outB;
  int lda, ldb, K;
};

template <int NJ>
__global__ __launch_bounds__(256) void k_gemm(GemmJob j0, GemmJob j1, GemmJob j2,
                                              int M, int ldf, int ldob, long obOff,
                                              int xcdswz) {
  GemmJob jb = j0;
  if (NJ > 1 && blockIdx.z == 1) jb = j1;
  if (NJ > 2 && blockIdx.z == 2) jb = j2;
  int m_i, n_i;
  if (xcdswz) {
    int L = blockIdx.x + (blockIdx.y << 3);
    int xcd = L & 7, j = L >> 3;
    n_i = j & 7;
    m_i = ((j >> 3) << 3) + xcd;
    if (m_i >= 157) return;
  } else {
    n_i = blockIdx.x; m_i = blockIdx.y;
  }
  const int m0 = m_i * 128, n0 = n_i * 128;

  __shared__ u16 lA[2][4096];
  __shared__ u16 lB[2][4096];
  const int tid = threadIdx.x;
  const int l = tid & 63;
  const int w = tid >> 6;
  const int wr = w >> 1, wc = w & 1;

  f32x4 acc[4][4];
  const f32x4 z = {0.f, 0.f, 0.f, 0.f};
#pragma unroll
  for (int i = 0; i < 4; i++)
#pragma unroll
    for (int j = 0; j < 4; j++) acc[i][j] = z;

  const u16* gA[2]; const u16* gB[2];
  int ldst[2];
#pragma unroll
  for (int q = 0; q < 2; q++) {
    int s = q * 256 + tid;
    int r = s >> 2, kc = s & 3;
    int ra = m0 + r; if (ra > M - 1) ra = M - 1;
    gA[q] = jb.A + (size_t)ra * jb.lda + kc * 8;
    gB[q] = jb.BT + (size_t)(n0 + r) * jb.ldb + kc * 8;
    ldst[q] = (q * 256 + w * 64) * 8;
  }

  const int fr = l & 15, qd = l >> 4;
  const int aro[4] = {(wr * 64 + 0 * 16 + fr) * 32 + qd * 8, (wr * 64 + 1 * 16 + fr) * 32 + qd * 8,
                      (wr * 64 + 2 * 16 + fr) * 32 + qd * 8, (wr * 64 + 3 * 16 + fr) * 32 + qd * 8};
  const int bro[4] = {(wc * 64 + 0 * 16 + fr) * 32 + qd * 8, (wc * 64 + 1 * 16 + fr) * 32 + qd * 8,
                      (wc * 64 + 2 * 16 + fr) * 32 + qd * 8, (wc * 64 + 3 * 16 + fr) * 32 + qd * 8};

  const int nit = jb.K >> 5;
#pragma unroll
  for (int q = 0; q < 2; q++) {
    gload_lds16(gA[q], &lA[0][0] + ldst[q]);
    gload_lds16(gB[q], &lB[0][0] + ldst[q]);
  }
  for (int i = 0; i < nit; i++) {
    __syncthreads();
    if (i + 1 < nit) {
      int nb = (i + 1) & 1, kt = (i + 1) * 32;
#pragma unroll
      for (int q = 0; q < 2; q++) {
        gload_lds16(gA[q] + kt, &lA[nb][0] + ldst[q]);
        gload_lds16(gB[q] + kt, &lB[nb][0] + ldst[q]);
      }
    }
    const u16* la = &lA[i & 1][0];
    const u16* lb = &lB[i & 1][0];
    short8 af[4], bf[4];
#pragma unroll
    for (int t = 0; t < 4; t++) {
      af[t] = *(const short8*)(la + aro[t]);
      bf[t] = *(const short8*)(lb + bro[t]);
    }
#pragma unroll
    for (int i2 = 0; i2 < 4; i2++)
#pragma unroll
      for (int j = 0; j < 4; j++)
        acc[i2][j] = __builtin_amdgcn_mfma_f32_16x16x32_bf16(af[i2], bf[j], acc[i2][j], 0, 0, 0);
  }

#pragma unroll
  for (int i = 0; i < 4; i++) {
#pragma unroll
    for (int r = 0; r < 4; r++) {
      int m = m0 + wr * 64 + i * 16 + qd * 4 + r;
      if (m < M) {
#pragma unroll
        for (int j = 0; j < 4; j++) {
          int n = n0 + wc * 64 + j * 16 + fr;
          float v = acc[i][j][r];
          if (jb.bias) v += jb.bias[n];
          if (jb.outF) jb.outF[(size_t)m * ldf + n] = v;
          if (jb.outB) jb.outB[(size_t)m * ldob + obOff + n] = f2bf(v);
        }
      }
    }
  }
}

// ------- GEMM8: 256x256 tile, BK=64, 8-wave, 4-phase/K-tile counted-vmcnt pipeline -------
// Waits: pre-loop WAITV(10)+BAR -> {A,B}[0]h0 visible to all waves at P0.
//   kt.P0: stage, WAITV(8)  (last tile: 0), BAR  -> {A,B}[kt]h1 visible at P1/P2.
//   kt.P3: stage, WAITV(10) (kt==nkt-2: 4), BAR  -> {A,B}[kt+1]h0 visible at next P0.

template <int MS, int NS>
__device__ __forceinline__ void mfma_q(f32x4 (&acc)[8][4], const short8 (&aq)[4][2],
                                       const short8 (&bq)[2][2][2]) {
  __builtin_amdgcn_s_setprio(1);
#pragma unroll
  for (int fm = 0; fm < 4; fm++)
#pragma unroll
    for (int fn = 0; fn < 2; fn++)
#pragma unroll
      for (int kk = 0; kk < 2; kk++)
        acc[MS * 4 + fm][NS * 2 + fn] = __builtin_amdgcn_mfma_f32_16x16x32_bf16(
            aq[fm][kk], bq[NS][fn][kk], acc[MS * 4 + fm][NS * 2 + fn], 0, 0, 0);
  __builtin_amdgcn_s_setprio(0);
}

__device__ __forceinline__ short8 ld8(const char* p) { return *(const short8*)p; }

__global__ __launch_bounds__(512, 2) void k_gemm8(const u16* __restrict__ A,
                                                  const u16* __restrict__ BT,
                                                  u16* __restrict__ outB,
                                                  int lda, int ldb, int ldob, int nkt) {
  __shared__ u16 lA[2][16384];   // 64KB
  __shared__ u16 lB[2][16384];   // 64KB
  const int m_i = (blockIdx.x << 3) + (blockIdx.y >> 2);
  const int n_i = blockIdx.y & 3;
  const int m0 = m_i * 256, n0 = n_i * 256;
  const int tid = threadIdx.x;
  const int l = tid & 63, w = tid >> 6;
  const int wr = w >> 2, wc = w & 3;        // 2 x 4 waves; wave tile 128 x 64
  const int fr = l & 15, qd = l >> 4;
  const int swzx = (fr & 7) << 4;           // read-side byte XOR

  char* lAc = (char*)&lA[0][0];
  char* lBc = (char*)&lB[0][0];

  const size_t ldaS = (size_t)lda, ldbS = (size_t)ldb;
  const int lr = tid >> 3;
  const int cl = (tid & 7) ^ (lr & 7);
  const u16* gA0 = A + (size_t)(m0 + lr) * ldaS + cl * 8;
  const u16* gB0 = BT + (size_t)(n0 + ((lr >> 5) << 6) + (lr & 31)) * ldbS + cl * 8;
  const int ldsW = (tid & ~63) << 4;        // wave-uniform byte base within (buf,h,q=0)

#define STG_A(h, bsel, kt2)                                                     \
  do {                                                                          \
    const u16* _g = gA0 + (size_t)(kt2) * 64 + (size_t)(h) * 64 * ldaS;         \
    char* _l = lAc + ((bsel) << 15) + ((h) << 14) + ldsW;                       \
    gload_lds16(_g, _l);                                                        \
    gload_lds16(_g + 128 * ldaS, _l + (1 << 13));                               \
  } while (0)
#define STG_B(h, bsel, kt2)                                                     \
  do {                                                                          \
    const u16* _g = gB0 + (size_t)(kt2) * 64 + (size_t)(h) * 32 * ldbS;         \
    char* _l = lBc + ((bsel) << 15) + ((h) << 14) + ldsW;                       \
    gload_lds16(_g, _l);                                                        \
    gload_lds16(_g + 128 * ldbS, _l + (1 << 13));                               \
  } while (0)
#define BAR() __builtin_amdgcn_s_barrier()
#define LGKM0()                                                                \
  do {                                                                         \
    asm volatile("s_waitcnt lgkmcnt(0)" ::: "memory");                         \
    __builtin_amdgcn_sched_barrier(0);                                         \
  } while (0)
#define WAITV(N) asm volatile("s_waitcnt vmcnt(" #N ")" ::: "memory")

  f32x4 acc[8][4];
  const f32x4 z = {0.f, 0.f, 0.f, 0.f};
#pragma unroll
  for (int i = 0; i < 8; i++)
#pragma unroll
    for (int j = 0; j < 4; j++) acc[i][j] = z;

  short8 aq[4][2];      // current msub A-frags [fmL][kk]
  short8 bq[2][2][2];   // B-frags [nsub][fnL][kk]

  const int aB = (wr << 13) + (fr << 7);    // rowgroup-base(wr) + fr row
  const int bB = (wc << 12) + (fr << 7);
  const int colb0 = ((qd << 4)) ^ swzx;           // kk=0
  const int colb1 = (64 + (qd << 4)) ^ swzx;      // kk=1

  STG_A(0, 0, 0); STG_B(0, 0, 0); STG_A(1, 0, 0); STG_B(1, 0, 0);
  STG_A(0, 1, 1); STG_B(0, 1, 1); STG_A(1, 1, 1);
  WAITV(10);
  BAR();

  for (int kt = 0; kt < nkt; ++kt) {
    const int buf = kt & 1, nb = buf ^ 1;
    const int bo = buf << 15;
    // ---- P0: Q(msub0, nsub0); 12 ds_reads; stage B[kt+1]h1; wait {A,B}[kt]h1
#pragma unroll
    for (int fmL = 0; fmL < 4; fmL++) {
      aq[fmL][0] = ld8(lAc + bo + aB + (fmL << 11) + colb0);
      aq[fmL][1] = ld8(lAc + bo + aB + (fmL << 11) + colb1);
    }
#pragma unroll
    for (int fnL = 0; fnL < 2; fnL++) {
      bq[0][fnL][0] = ld8(lBc + bo + bB + (fnL << 11) + colb0);
      bq[0][fnL][1] = ld8(lBc + bo + bB + (fnL << 11) + colb1);
    }
    if (kt + 1 < nkt) { STG_B(1, nb, kt + 1); }
    if (kt == nkt - 1) { WAITV(0); } else { WAITV(8); }
    BAR(); LGKM0();
    mfma_q<0, 0>(acc, aq, bq);
    BAR();
    // ---- P1: Q(msub0, nsub1); 4 ds_reads; stage A[kt+2]h0
#pragma unroll
    for (int fnL = 0; fnL < 2; fnL++) {
      bq[1][fnL][0] = ld8(lBc + bo + bB + (1 << 14) + (fnL << 11) + colb0);
      bq[1][fnL][1] = ld8(lBc + bo + bB + (1 << 14) + (fnL << 11) + colb1);
    }
    if (kt + 2 < nkt) { STG_A(0, buf, kt + 2); }
    BAR(); LGKM0();
    mfma_q<0, 1>(acc, aq, bq);
    BAR();
    // ---- P2: Q(msub1, nsub1); 8 ds_reads (A msub1); stage B[kt+2]h0
#pragma unroll
    for (int fmL = 0; fmL < 4; fmL++) {
      aq[fmL][0] = ld8(lAc + bo + aB + (1 << 14) + (fmL << 11) + colb0);
      aq[fmL][1] = ld8(lAc + bo + aB + (1 << 14) + (fmL << 11) + colb1);
    }
    if (kt + 2 < nkt) { STG_B(0, buf, kt + 2); }
    BAR(); LGKM0();
    mfma_q<1, 1>(acc, aq, bq);
    BAR();
    // ---- P3: Q(msub1, nsub0); no ds_reads; stage A[kt+2]h1; wait {A,B}[kt+1]h0
    if (kt + 2 < nkt) { STG_A(1, buf, kt + 2); }
    if (kt < nkt - 2) { WAITV(10); }
    else if (kt == nkt - 2) { WAITV(4); }
    BAR(); LGKM0();
    mfma_q<1, 0>(acc, aq, bq);
    BAR();
  }

#undef STG_A
#undef STG_B
#undef BAR
#undef LGKM0
#undef WAITV

  const int mBase = m0 + wr * 128 + qd * 4;
  const int nBase = n0 + wc * 64 + fr;
#pragma unroll
  for (int fm = 0; fm < 8; fm++)
#pragma unroll
    for (int fn = 0; fn < 4; fn++)
#pragma unroll
      for (int r = 0; r < 4; r++)
        outB[(size_t)(mBase + fm * 16 + r) * ldob + nBase + fn * 16] = f2bf(acc[fm][fn][r]);
}

// ---------------- aggregation (pull, wave per node, 4-edge unrolled) ----------------

struct AggJob {
  const u16* H;
  const int* offs; const int* csrc; const float* cw; const float* dinv;
  const float* bias;
  float* outF; u16* outB;
  long obOff; int colOff;
};

template <int CPL>
__global__ void k_agg(AggJob j0, AggJob j1, AggJob j2, int ldh, int ldf, int ldob,
                      int relu) {
  AggJob jb = j0;
  if (blockIdx.y == 1) jb = j1;
  if (blockIdx.y == 2) jb = j2;
  int wid = blockIdx.x * (blockDim.x >> 6) + (threadIdx.x >> 6);
  if (wid >= NN) return;
  int l = threadIdx.x & 63;
  const u16* hbase = jb.H + jb.colOff + (size_t)l * CPL;
  float acc[CPL], f0[CPL], f1[CPL], f2[CPL], f3[CPL];
  float dv = jb.dinv[wid];
  float sw = dv * dv;
  if (CPL == 8) ld_bf16x8(hbase + (size_t)wid * ldh, f0);
  else          ld_bf16x4(hbase + (size_t)wid * ldh, f0);
#pragma unroll
  for (int j = 0; j < CPL; j++) acc[j] = f0[j] * sw;
  int e = jb.offs[wid], e1 = jb.offs[wid + 1];
  for (; e + 4 <= e1; e += 4) {
    int s0 = jb.csrc[e], s1 = jb.csrc[e + 1], s2 = jb.csrc[e + 2], s3 = jb.csrc[e + 3];
    float w0 = jb.cw[e], w1 = jb.cw[e + 1], w2 = jb.cw[e + 2], w3 = jb.cw[e + 3];
    if (CPL == 8) {
      ld_bf16x8(hbase + (size_t)s0 * ldh, f0); ld_bf16x8(hbase + (size_t)s1 * ldh, f1);
      ld_bf16x8(hbase + (size_t)s2 * ldh, f2); ld_bf16x8(hbase + (size_t)s3 * ldh, f3);
    } else {
      ld_bf16x4(hbase + (size_t)s0 * ldh, f0); ld_bf16x4(hbase + (size_t)s1 * ldh, f1);
      ld_bf16x4(hbase + (size_t)s2 * ldh, f2); ld_bf16x4(hbase + (size_t)s3 * ldh, f3);
    }
#pragma unroll
    for (int j = 0; j < CPL; j++) acc[j] += f0[j] * w0;
#pragma unroll
    for (int j = 0; j < CPL; j++) acc[j] += f1[j] * w1;
#pragma unroll
    for (int j = 0; j < CPL; j++) acc[j] += f2[j] * w2;
#pragma unroll
    for (int j = 0; j < CPL; j++) acc[j] += f3[j] * w3;
  }
  for (; e < e1; ++e) {
    int s0 = jb.csrc[e];
    float w0 = jb.cw[e];
    if (CPL == 8) ld_bf16x8(hbase + (size_t)s0 * ldh, f0);
    else          ld_bf16x4(hbase + (size_t)s0 * ldh, f0);
#pragma unroll
    for (int j = 0; j < CPL; j++) acc[j] += f0[j] * w0;
  }
  const float* bp = jb.bias + l * CPL;
#pragma unroll
  for (int j = 0; j < CPL; j++) {
    float v = acc[j] + bp[j];
    if (relu) v = v > 0.f ? v : 0.f;
    acc[j] = v;
  }
  if (jb.outF) {
    float* q = jb.outF + (size_t)wid * ldf + l * CPL;
#pragma unroll
    for (int j = 0; j < CPL; j++) q[j] = acc[j];
  }
  if (jb.outB) {
    u16* q = jb.outB + (size_t)wid * ldob + jb.obOff + l * CPL;
#pragma unroll
    for (int j = 0; j < CPL; j++) q[j] = f2bf(acc[j]);
  }
}

// ---------------- launch ----------------

extern "C" void kernel_launch(void* const* d_in, const int* in_sizes, int n_in,
                              void* d_out, int out_size, void* d_ws, size_t ws_size,
                              hipStream_t stream) {
  (void)in_sizes; (void)n_in; (void)out_size; (void)ws_size;
  const float* x_RNA = (const float*)d_in[0];
  const float* x_ADT = (const float*)d_in[1];
  EJobs ej;
  ej.ei[0] = (const int*)d_in[2]; ej.ew[0] = (const float*)d_in[3];
  ej.ei[1] = (const int*)d_in[4]; ej.ew[1] = (const float*)d_in[5];
  ej.ei[2] = (const int*)d_in[6]; ej.ew[2] = (const float*)d_in[7];
  const float* W_rna1 = (const float*)d_in[8];  const float* b_rna1 = (const float*)d_in[9];
  const float* W_rna2 = (const float*)d_in[10]; const float* b_rna2 = (const float*)d_in[11];
  const float* W_p3   = (const float*)d_in[12]; const float* b_p3   = (const float*)d_in[13];
  const float* W_sim  = (const float*)d_in[14]; const float* b_sim  = (const float*)d_in[15];
  const float* W_dist = (const float*)d_in[16]; const float* b_dist = (const float*)d_in[17];
  const float* W_f1   = (const float*)d_in[18]; const float* b_f1   = (const float*)d_in[19];
  const float* W_f2   = (const float*)d_in[20]; const float* b_f2   = (const float*)d_in[21];
  float* out = (float*)d_out;

  char* p = (char*)d_ws;
  auto alloc = [&](size_t bytes) {
    char* r = p;
    p += (bytes + 255) & ~(size_t)255;
    return r;
  };
  u16* WcT   = (u16*)alloc((size_t)1024 * KX * 2);
  u16* WsT   = (u16*)alloc((size_t)OUTC * HID * 2);
  u16* WdT   = (u16*)alloc((size_t)OUTC * HID * 2);
  u16* Wf1T  = (u16*)alloc((size_t)OUTC * HID * 2);
  u16* Wp3T  = (u16*)alloc((size_t)OUTC * KQ * 2);
  u16* WcatT = (u16*)alloc((size_t)OUTC * 768 * 2);
  float* bias2 = (float*)alloc(OUTC * 4);
  u16* ADTb = (u16*)alloc((size_t)NN * KQ * 2);
  u16* H1   = (u16*)alloc((size_t)NN * 1024 * 2);  // later: H2s|H2d|H2p
  u16* B2   = (u16*)alloc((size_t)NN * 1024 * 2);  // XS|XD, later XSDP
  float* deg = (float*)alloc((size_t)3 * NN * 4);
  int* cnt   = (int*)alloc((size_t)3 * NN * 4);
  int* offs  = (int*)alloc((size_t)3 * (NN + 1) * 4);
  int* csrc  = (int*)alloc((size_t)3 * NE * 4);
  float* cwn = (float*)alloc((size_t)3 * NE * 4);
  int* part  = (int*)alloc(3 * 128 * 4);

  u16* Xb   = (u16*)d_out;   // bf16 x_RNA scratch: dead before first f32 output write
  u16* XS   = B2;
  u16* XD   = B2 + (size_t)NN * 512;
  u16* XSDP = B2;            // [NN, 768] = x_sim | x_dist | pro (bf16), after A2
  u16* H2s  = H1;
  u16* H2d  = H1 + (size_t)NN * 256;
  u16* H2p  = H1 + (size_t)NN * 512;

  // CSR replica state carved from B2 (B2 is dead until A1, which runs after fill):
  // degR | cntR | curR (contiguous, zeroed by k_zero) then subO (written by scan_a)
  int* wsCsr  = (int*)B2;
  float* degR = (float*)wsCsr;                  // [NREP][3][NN]
  int*   cntR = wsCsr + NREP * 3 * NN;
  int*   curR = wsCsr + 2 * NREP * 3 * NN;
  int*   subO = wsCsr + 3 * NREP * 3 * NN;

  const int T = 256;
  // zero replica state first (prep's EC round atomically accumulates into it)
  k_zero<<<(3 * NREP * 3 * NN / 4 + 255) / 256, T, 0, stream>>>((uint4*)wsCsr);

  Prep P;
  P.xR = x_RNA; P.xA = x_ADT; P.W1 = W_rna1; P.W2 = W_rna2;
  P.Ws0 = W_sim; P.Ws1 = W_dist; P.Ws2 = W_f1; P.Ws3 = W_f2; P.Ws4 = W_p3;
  P.Wo0 = WsT; P.Wo1 = WdT; P.Wo2 = Wf1T; P.Wo3 = nullptr; P.Wo4 = Wp3T;
  P.bf1 = b_f1; P.bf2 = b_f2;
  P.Xb = Xb; P.ADTb = ADTb; P.WcT = WcT; P.WcatT = WcatT; P.bias2 = bias2;
  P.ej = ej; P.degR = degR; P.cntR = cntR;
  P.Wo3 = (u16*)(cwn);  // dead scratch until k_fill_csr3; wT5 finishes in k_prep before it
  k_prep<<<26553, T, 0, stream>>>(P);

  k_scan_a<<<dim3(NB79, 3), 256, 0, stream>>>(degR, cntR, subO, deg, cnt, part);
  k_scan_b<<<1, 128, 0, stream>>>(part);
  k_scan_c<<<dim3(NB79, 3), 256, 0, stream>>>(cnt, part, offs);
  k_fill_csr3<<<dim3((NE + T - 1) / T, 3), T, 0, stream>>>(ej, deg, offs, subO, curR, csrc, cwn);

  GemmJob jz = {};
  // G1 main: rows [0,16384) = 64 full 256-tiles x 4 n-tiles = 256 blocks (1 round, 1 blk/CU)
  k_gemm8<<<dim3(8, 32), 512, 0, stream>>>(Xb, WcT, H1, KX, KX, 1024, KX >> 6);
  // G1 tail: rows [16384,20000) on the 128^2 kernel (29 x 8 = 232 blocks)
  GemmJob g1t = {Xb + (size_t)16384 * KX, WcT, nullptr, nullptr, H1 + (size_t)16384 * 1024,
                 KX, KX, KX};
  k_gemm<1><<<dim3(8, 29), 256, 0, stream>>>(g1t, jz, jz, NN - 16384, 0, 1024, 0, 0);
  // A1: XS = relu(agg_sim(H1[:,:512]) + b_rna1); XD likewise (dist)
  AggJob a0 = {H1, offs, csrc, cwn, deg, b_rna1, nullptr, XS, 0, 0};
  AggJob a1 = {H1, offs + (NN + 1), csrc + NE, cwn + NE, deg + NN, b_rna2, nullptr, XD, 0, 512};
  k_agg<8><<<dim3(NN / 4, 2), 256, 0, stream>>>(a0, a1, a1, 1024, 0, 512, 1);
  // G2: H2s=XS@W_sim, H2d=XD@W_dist, H2p=ADTb@W_p3
  GemmJob g2a = {XS, WsT, nullptr, nullptr, H2s, HID, HID, HID};
  GemmJob g2b = {XD, WdT, nullptr, nullptr, H2d, HID, HID, HID};
  GemmJob g2c = {ADTb, Wp3T, nullptr, nullptr, H2p, KQ, KQ, KQ};
  k_gemm<3><<<dim3(2, 157, 3), 256, 0, stream>>>(g2a, g2b, g2c, NN, 0, 256, 0, 0);
  // A2: x_sim, x_dist, pro -> f32 outputs + bf16 into XSDP
  AggJob b0 = {H2s, offs, csrc, cwn, deg, b_sim, out, XSDP, 0, 0};
  AggJob b1 = {H2d, offs + (NN + 1), csrc + NE, cwn + NE, deg + NN, b_dist,
               out + OUTSZ, XSDP, 256, 0};
  AggJob b2 = {H2p, offs + 2 * (NN + 1), csrc + 2 * NE, cwn + 2 * NE, deg + 2 * NN, b_p3,
               out + 4 * OUTSZ, XSDP, 512, 0};
  k_agg<4><<<dim3(NN / 4, 3), 256, 0, stream>>>(b0, b1, b2, 256, 256, 768, 0);
  // G5 (2 jobs): fused = XSDP[:,:512]@W_f1 + b_f1 ; fused_pro = XSDP@Wcat + bias2
  GemmJob g5a = {XSDP, Wf1T, b_f1, out + 2 * OUTSZ, nullptr, 768, 512, 512};
  GemmJob g5b = {XSDP, WcatT, bias2, out + 3 * OUTSZ, nullptr, 768, 768, 768};
  k_gemm<2><<<dim3(2, 157, 2), 256, 0, stream>>>(g5a, g5b, jz, NN, 256, 0, 0, 0);
}

// Round 7
// 765.914 us; speedup vs baseline: 1.0999x; 1.0450x over previous
//
#include <hip/hip_runtime.h>

#define AS1 __attribute__((address_space(1)))
#define AS3 __attribute__((address_space(3)))

typedef __attribute__((ext_vector_type(8))) short short8;
typedef __attribute__((ext_vector_type(4))) float f32x4;
typedef unsigned int u32;
typedef unsigned short u16;
typedef unsigned long long u64;

static constexpr int NN = 20000;
static constexpr int NE = 320000;
static constexpr int INC = 2000;
static constexpr int KX = 2048;
static constexpr int HID = 512;
static constexpr int OUTC = 256;
static constexpr int QA = 100;
static constexpr int KQ = 128;
static constexpr long OUTSZ = (long)NN * OUTC;
static constexpr int NB79 = (NN + 255) / 256;   // 79
static constexpr int NREP = 8;                  // CSR atomic replicas

__device__ __forceinline__ u16 f2bf(float f) {
  u32 u = __float_as_uint(f);
  u = (u + 0x7FFFu + ((u >> 16) & 1u)) >> 16;   // RNE
  return (u16)u;
}
__device__ __forceinline__ void ld_bf16x8(const u16* p, float* f) {
  uint4 r = *(const uint4*)p;
  f[0] = __uint_as_float(r.x << 16); f[1] = __uint_as_float(r.x & 0xFFFF0000u);
  f[2] = __uint_as_float(r.y << 16); f[3] = __uint_as_float(r.y & 0xFFFF0000u);
  f[4] = __uint_as_float(r.z << 16); f[5] = __uint_as_float(r.z & 0xFFFF0000u);
  f[6] = __uint_as_float(r.w << 16); f[7] = __uint_as_float(r.w & 0xFFFF0000u);
}
__device__ __forceinline__ void ld_bf16x4(const u16* p, float* f) {
  uint2 r = *(const uint2*)p;
  f[0] = __uint_as_float(r.x << 16); f[1] = __uint_as_float(r.x & 0xFFFF0000u);
  f[2] = __uint_as_float(r.y << 16); f[3] = __uint_as_float(r.y & 0xFFFF0000u);
}

struct EJobs { const int* ei[3]; const float* ew[3]; };

// ---------------- fused prep kernel ----------------
// R4 [0,769): Wcat compose + bias2 ; R2 [769,1041): wT5 ; R3 [1041,1553): WcT transpose
// EC [1553,5303): edge count, ONE packed u64 atomic/edge (cnt<<48 | deg_fix32)
// R1 [5303,6553): x_ADT cast ; R0 [6553,26553): x_RNA cast (BW-dominant)
struct Prep {
  const float *xR, *xA;
  const float *W1, *W2;                     // W_rna1, W_rna2
  const float *Ws0, *Ws1, *Ws2, *Ws3, *Ws4; // W_sim, W_dist, W_f1, W_f2, W_p3
  u16 *Wo0, *Wo1, *Wo2, *Wo3, *Wo4;
  const float *bf1, *bf2;
  u16 *Xb, *ADTb, *WcT, *WcatT;
  float *bias2;
  EJobs ej; u64* dcR;                       // packed (cnt,deg) replicas
};

__global__ __launch_bounds__(256) void k_prep(Prep P) {
  int b = blockIdx.x, t = threadIdx.x;
  if (b < 769) {                         // ---- R4: Wcat compose
    int k = b, n = t;
    if (k < 512) {
      __shared__ float w2row[256];
      w2row[t] = P.Ws2[k * OUTC + t];
      __syncthreads();
      float s0 = 0.f, s1 = 0.f, s2 = 0.f, s3 = 0.f;
      float s4 = 0.f, s5 = 0.f, s6 = 0.f, s7 = 0.f;
      for (int j = 0; j < 256; j += 8) {
        s0 += w2row[j + 0] * P.Ws3[(j + 0) * OUTC + n];
        s1 += w2row[j + 1] * P.Ws3[(j + 1) * OUTC + n];
        s2 += w2row[j + 2] * P.Ws3[(j + 2) * OUTC + n];
        s3 += w2row[j + 3] * P.Ws3[(j + 3) * OUTC + n];
        s4 += w2row[j + 4] * P.Ws3[(j + 4) * OUTC + n];
        s5 += w2row[j + 5] * P.Ws3[(j + 5) * OUTC + n];
        s6 += w2row[j + 6] * P.Ws3[(j + 6) * OUTC + n];
        s7 += w2row[j + 7] * P.Ws3[(j + 7) * OUTC + n];
      }
      float s = ((s0 + s1) + (s2 + s3)) + ((s4 + s5) + (s6 + s7));
      P.WcatT[(long)n * 768 + k] = f2bf(s);
    } else if (k < 768) {
      P.WcatT[(long)n * 768 + k] = f2bf(P.Ws3[(256 + k - 512) * OUTC + n]);
    } else {
      float s0 = 0.f, s1 = 0.f, s2 = 0.f, s3 = 0.f;
      for (int j = 0; j < 256; j += 4) {
        s0 += P.bf1[j + 0] * P.Ws3[(j + 0) * OUTC + n];
        s1 += P.bf1[j + 1] * P.Ws3[(j + 1) * OUTC + n];
        s2 += P.bf1[j + 2] * P.Ws3[(j + 2) * OUTC + n];
        s3 += P.bf1[j + 3] * P.Ws3[(j + 3) * OUTC + n];
      }
      P.bias2[n] = P.bf2[n] + ((s0 + s1) + (s2 + s3));
    }
    return;
  }
  if (b < 1041) {                        // ---- R2: wT5
    int slot = (b - 769) * 256 + t;
    const float* W; u16* o; int Kin, Kpad, within;
    if (slot < 65536) {
      int j = slot >> 14; within = slot & 16383;
      W = (j == 0) ? P.Ws0 : (j == 1) ? P.Ws1 : (j == 2) ? P.Ws2 : P.Ws3;
      o = (j == 0) ? P.Wo0 : (j == 1) ? P.Wo1 : (j == 2) ? P.Wo2 : P.Wo3;
      Kin = HID; Kpad = HID;
    } else {
      within = slot - 65536; W = P.Ws4; o = P.Wo4; Kin = QA; Kpad = KQ;
    }
    int kg = Kpad >> 3;
    int n = within / kg, k8 = (within % kg) << 3;
    u16 v[8];
#pragma unroll
    for (int j = 0; j < 8; j++) {
      int k = k8 + j;
      v[j] = (k < Kin) ? f2bf(W[(long)k * OUTC + n]) : (u16)0;
    }
    *(uint4*)(o + (long)n * Kpad + k8) = *(const uint4*)v;
    return;
  }
  if (b < 1553) {                        // ---- R3: WcT transpose
    __shared__ float tile[64][65];
    int bb = b - 1041;
    int kb = (bb & 31) * 64, nb = (bb >> 5) * 64;
    const float* W = (nb < HID) ? P.W1 : P.W2;
    int nb2 = nb & (HID - 1);
#pragma unroll
    for (int p = 0; p < 4; p++) {
      int idx = p * 256 + t;
      int r = idx >> 4, c4 = (idx & 15) << 2;
      int k = kb + r;
      float4 v = {0.f, 0.f, 0.f, 0.f};
      if (k < INC) v = *(const float4*)(W + (long)k * HID + nb2 + c4);
      tile[r][c4] = v.x; tile[r][c4 + 1] = v.y; tile[r][c4 + 2] = v.z; tile[r][c4 + 3] = v.w;
    }
    __syncthreads();
#pragma unroll
    for (int p = 0; p < 2; p++) {
      int idx = p * 256 + t;
      int n = idx >> 3, kg = (idx & 7) << 3;
      u16 v[8];
#pragma unroll
      for (int j = 0; j < 8; j++) v[j] = f2bf(tile[kg + j][n]);
      *(uint4*)(P.WcT + (long)(nb + n) * KX + kb + kg) = *(const uint4*)v;
    }
    return;
  }
  if (b < 5303) {                        // ---- EC: edge count (packed u64 atomic)
    int idx = b - 1553;
    int g = idx / 1250, eb = idx - g * 1250;   // eb in [0,1250)
    int e = eb * 256 + t;                      // 1250*256 == NE exactly
    int s = eb & (NREP - 1);                   // must match k_fill_csr3's mapping
    int base = (s * 3 + g) * NN;
    int dst = P.ej.ei[g][NE + e];
    float w = P.ej.ew[g][e];
    u64 pk = (1ULL << 48) | (u64)((double)w * 4294967296.0 + 0.5);
    atomicAdd(&P.dcR[base + dst], pk);
    return;
  }
  if (b < 6553) {                        // ---- R1: x_ADT cast, 16 rows/block
    int row = (b - 5303) * 16 + (t >> 4);
    int c8 = (t & 15) << 3;
    u16 v[8];
#pragma unroll
    for (int j = 0; j < 8; j++) {
      int c = c8 + j;
      v[j] = (c < QA) ? f2bf(P.xA[(long)row * QA + c]) : (u16)0;
    }
    *(uint4*)(P.ADTb + (long)row * KQ + c8) = *(const uint4*)v;
    return;
  }
  {                                      // ---- R0: x_RNA row cast
    int row = b - 6553;
    int c8 = t << 3;
    u16 v[8];
    if (c8 + 8 <= INC) {
      const float4* p = (const float4*)(P.xR + (long)row * INC + c8);
      float4 a = p[0], c = p[1];
      v[0] = f2bf(a.x); v[1] = f2bf(a.y); v[2] = f2bf(a.z); v[3] = f2bf(a.w);
      v[4] = f2bf(c.x); v[5] = f2bf(c.y); v[6] = f2bf(c.z); v[7] = f2bf(c.w);
    } else {
#pragma unroll
      for (int j = 0; j < 8; j++) {
        int c = c8 + j;
        v[j] = (c < INC) ? f2bf(P.xR[(long)row * INC + c]) : (u16)0;
      }
    }
    *(uint4*)(P.Xb + (long)row * KX + c8) = *(const uint4*)v;
  }
}

// ---------------- CSR build ----------------

// reduce replicas -> dinv, total cnt, per-replica exclusive sub-offsets; block sums.
__global__ void k_scan_a(const u64* __restrict__ dcR, int* __restrict__ subO,
                         float* __restrict__ deg, int* __restrict__ cnt,
                         int* __restrict__ part) {
  __shared__ int buf[256];
  int g = blockIdx.y, b = blockIdx.x, t = threadIdx.x;
  int i = b * 256 + t;
  int v = 0;
  if (i < NN) {
    u64 dfix = 0;
    int c = 0;
#pragma unroll
    for (int s = 0; s < NREP; s++) {
      int idx = (s * 3 + g) * NN + i;
      u64 pv = dcR[idx];
      subO[idx] = c;
      c += (int)(pv >> 48);
      dfix += pv & 0xFFFFFFFFFFFFULL;
    }
    double dd = 1.0 + (double)dfix * (1.0 / 4294967296.0);   // self loop + fixed-point sum
    deg[g * NN + i] = rsqrtf((float)dd);
    cnt[g * NN + i] = c;
    v = c;
  }
  buf[t] = v;
  __syncthreads();
  for (int off = 128; off > 0; off >>= 1) {
    if (t < off) buf[t] += buf[t + off];
    __syncthreads();
  }
  if (t == 0) part[g * 128 + b] = buf[0];
}
__global__ void k_scan_b(int* part) {
  __shared__ int buf[128];
  int t = threadIdx.x;
  for (int g = 0; g < 3; g++) {
    int v = part[g * 128 + t];
    buf[t] = v;
    __syncthreads();
    for (int off = 1; off < 128; off <<= 1) {
      int u = (t >= off) ? buf[t - off] : 0;
      __syncthreads();
      buf[t] += u;
      __syncthreads();
    }
    part[g * 128 + t] = buf[t] - v;
    __syncthreads();
  }
}
__global__ void k_scan_c(const int* __restrict__ cnt, const int* __restrict__ part,
                         int* __restrict__ offs) {
  __shared__ int buf[256];
  int g = blockIdx.y, b = blockIdx.x, t = threadIdx.x;
  int i = b * 256 + t;
  int v = (i < NN) ? cnt[g * NN + i] : 0;
  buf[t] = v;
  __syncthreads();
  for (int off = 1; off < 256; off <<= 1) {
    int u = (t >= off) ? buf[t - off] : 0;
    __syncthreads();
    buf[t] += u;
    __syncthreads();
  }
  int base = part[g * 128 + b];
  int excl = base + buf[t] - v;
  if (i < NN) offs[g * (NN + 1) + i] = excl;
  if (i == NN - 1) offs[g * (NN + 1) + NN] = excl + v;
}
__global__ void k_fill_csr3(EJobs js, const float* __restrict__ dinv,
                            const int* __restrict__ offs, const int* __restrict__ subO,
                            int* curR, int* csrc, float* cw) {
  int g = blockIdx.y;
  int e = blockIdx.x * blockDim.x + threadIdx.x;
  if (e >= NE) return;
  int s = blockIdx.x & (NREP - 1);        // must match prep EC's mapping
  int sIdx = (s * 3 + g) * NN;
  int src = js.ei[g][e], d = js.ei[g][NE + e];
  float w = js.ew[g][e];
  int pos = offs[g * (NN + 1) + d] + subO[sIdx + d] + atomicAdd(&curR[sIdx + d], 1);
  csrc[g * NE + pos] = src;
  cw[g * NE + pos] = dinv[g * NN + src] * w * dinv[g * NN + d];
}

// ------- GEMM: bf16 MFMA 128x128 tile, BK=32, double-buffered LDS, 1 barrier/iter -------

__device__ __forceinline__ void gload_lds16(const void* g, void* l) {
  __builtin_amdgcn_global_load_lds((const AS1 void*)g, (AS3 void*)l, 16, 0, 0);
}

struct GemmJob {
  const u16* A; const u16* BT; const float* bias;
  float* outF; u16* outB;
  int lda, ldb, K;
};

template <int NJ>
__global__ __launch_bounds__(256) void k_gemm(GemmJob j0, GemmJob j1, GemmJob j2,
                                              int M, int ldf, int ldob, long obOff,
                                              int xcdswz) {
  GemmJob jb = j0;
  if (NJ > 1 && blockIdx.z == 1) jb = j1;
  if (NJ > 2 && blockIdx.z == 2) jb = j2;
  int m_i, n_i;
  if (xcdswz) {
    int L = blockIdx.x + (blockIdx.y << 3);
    int xcd = L & 7, j = L >> 3;
    n_i = j & 7;
    m_i = ((j >> 3) << 3) + xcd;
    if (m_i >= 157) return;
  } else {
    n_i = blockIdx.x; m_i = blockIdx.y;
  }
  const int m0 = m_i * 128, n0 = n_i * 128;

  __shared__ u16 lA[2][4096];
  __shared__ u16 lB[2][4096];
  const int tid = threadIdx.x;
  const int l = tid & 63;
  const int w = tid >> 6;
  const int wr = w >> 1, wc = w & 1;

  f32x4 acc[4][4];
  const f32x4 z = {0.f, 0.f, 0.f, 0.f};
#pragma unroll
  for (int i = 0; i < 4; i++)
#pragma unroll
    for (int j = 0; j < 4; j++) acc[i][j] = z;

  const u16* gA[2]; const u16* gB[2];
  int ldst[2];
#pragma unroll
  for (int q = 0; q < 2; q++) {
    int s = q * 256 + tid;
    int r = s >> 2, kc = s & 3;
    int ra = m0 + r; if (ra > M - 1) ra = M - 1;
    gA[q] = jb.A + (size_t)ra * jb.lda + kc * 8;
    gB[q] = jb.BT + (size_t)(n0 + r) * jb.ldb + kc * 8;
    ldst[q] = (q * 256 + w * 64) * 8;
  }

  const int fr = l & 15, qd = l >> 4;
  const int aro[4] = {(wr * 64 + 0 * 16 + fr) * 32 + qd * 8, (wr * 64 + 1 * 16 + fr) * 32 + qd * 8,
                      (wr * 64 + 2 * 16 + fr) * 32 + qd * 8, (wr * 64 + 3 * 16 + fr) * 32 + qd * 8};
  const int bro[4] = {(wc * 64 + 0 * 16 + fr) * 32 + qd * 8, (wc * 64 + 1 * 16 + fr) * 32 + qd * 8,
                      (wc * 64 + 2 * 16 + fr) * 32 + qd * 8, (wc * 64 + 3 * 16 + fr) * 32 + qd * 8};

  const int nit = jb.K >> 5;
#pragma unroll
  for (int q = 0; q < 2; q++) {
    gload_lds16(gA[q], &lA[0][0] + ldst[q]);
    gload_lds16(gB[q], &lB[0][0] + ldst[q]);
  }
  for (int i = 0; i < nit; i++) {
    __syncthreads();
    if (i + 1 < nit) {
      int nb = (i + 1) & 1, kt = (i + 1) * 32;
#pragma unroll
      for (int q = 0; q < 2; q++) {
        gload_lds16(gA[q] + kt, &lA[nb][0] + ldst[q]);
        gload_lds16(gB[q] + kt, &lB[nb][0] + ldst[q]);
      }
    }
    const u16* la = &lA[i & 1][0];
    const u16* lb = &lB[i & 1][0];
    short8 af[4], bf[4];
#pragma unroll
    for (int t = 0; t < 4; t++) {
      af[t] = *(const short8*)(la + aro[t]);
      bf[t] = *(const short8*)(lb + bro[t]);
    }
#pragma unroll
    for (int i2 = 0; i2 < 4; i2++)
#pragma unroll
      for (int j = 0; j < 4; j++)
        acc[i2][j] = __builtin_amdgcn_mfma_f32_16x16x32_bf16(af[i2], bf[j], acc[i2][j], 0, 0, 0);
  }

#pragma unroll
  for (int i = 0; i < 4; i++) {
#pragma unroll
    for (int r = 0; r < 4; r++) {
      int m = m0 + wr * 64 + i * 16 + qd * 4 + r;
      if (m < M) {
#pragma unroll
        for (int j = 0; j < 4; j++) {
          int n = n0 + wc * 64 + j * 16 + fr;
          float v = acc[i][j][r];
          if (jb.bias) v += jb.bias[n];
          if (jb.outF) jb.outF[(size_t)m * ldf + n] = v;
          if (jb.outB) jb.outB[(size_t)m * ldob + obOff + n] = f2bf(v);
        }
      }
    }
  }
}

// ------- GEMM8: 256x256 tile, BK=64, 8-wave, 4-phase/K-tile counted-vmcnt pipeline -------
// Now covers ALL of M (grid (8,40): m_i = bx*10 + by>>2, 79 active m-tiles).
// Ragged last tile: staging reads rows up to 20223 (still inside d_out's 102MB
// allocation — harmless garbage), epilogue guards mrow < M. Accumulation order
// identical to the old 128^2 tail kernel -> bitwise-same results.
// Waits: pre-loop WAITV(10)+BAR -> {A,B}[0]h0 visible to all waves at P0.
//   kt.P0: stage, WAITV(8)  (last tile: 0), BAR  -> {A,B}[kt]h1 visible at P1/P2.
//   kt.P3: stage, WAITV(10) (kt==nkt-2: 4), BAR  -> {A,B}[kt+1]h0 visible at next P0.

template <int MS, int NS>
__device__ __forceinline__ void mfma_q(f32x4 (&acc)[8][4], const short8 (&aq)[4][2],
                                       const short8 (&bq)[2][2][2]) {
  __builtin_amdgcn_s_setprio(1);
#pragma unroll
  for (int fm = 0; fm < 4; fm++)
#pragma unroll
    for (int fn = 0; fn < 2; fn++)
#pragma unroll
      for (int kk = 0; kk < 2; kk++)
        acc[MS * 4 + fm][NS * 2 + fn] = __builtin_amdgcn_mfma_f32_16x16x32_bf16(
            aq[fm][kk], bq[NS][fn][kk], acc[MS * 4 + fm][NS * 2 + fn], 0, 0, 0);
  __builtin_amdgcn_s_setprio(0);
}

__device__ __forceinline__ short8 ld8(const char* p) { return *(const short8*)p; }

__global__ __launch_bounds__(512, 2) void k_gemm8(const u16* __restrict__ A,
                                                  const u16* __restrict__ BT,
                                                  u16* __restrict__ outB,
                                                  int lda, int ldb, int ldob, int nkt,
                                                  int M) {
  __shared__ u16 lA[2][16384];   // 64KB
  __shared__ u16 lB[2][16384];   // 64KB
  const int m_i = blockIdx.x * 10 + (blockIdx.y >> 2);
  const int n_i = blockIdx.y & 3;
  const int m0 = m_i * 256, n0 = n_i * 256;
  if (m0 >= M) return;
  const int tid = threadIdx.x;
  const int l = tid & 63, w = tid >> 6;
  const int wr = w >> 2, wc = w & 3;        // 2 x 4 waves; wave tile 128 x 64
  const int fr = l & 15, qd = l >> 4;
  const int swzx = (fr & 7) << 4;           // read-side byte XOR

  char* lAc = (char*)&lA[0][0];
  char* lBc = (char*)&lB[0][0];

  const size_t ldaS = (size_t)lda, ldbS = (size_t)ldb;
  const int lr = tid >> 3;
  const int cl = (tid & 7) ^ (lr & 7);
  const u16* gA0 = A + (size_t)(m0 + lr) * ldaS + cl * 8;
  const u16* gB0 = BT + (size_t)(n0 + ((lr >> 5) << 6) + (lr & 31)) * ldbS + cl * 8;
  const int ldsW = (tid & ~63) << 4;        // wave-uniform byte base within (buf,h,q=0)

#define STG_A(h, bsel, kt2)                                                     \
  do {                                                                          \
    const u16* _g = gA0 + (size_t)(kt2) * 64 + (size_t)(h) * 64 * ldaS;         \
    char* _l = lAc + ((bsel) << 15) + ((h) << 14) + ldsW;                       \
    gload_lds16(_g, _l);                                                        \
    gload_lds16(_g + 128 * ldaS, _l + (1 << 13));                               \
  } while (0)
#define STG_B(h, bsel, kt2)                                                     \
  do {                                                                          \
    const u16* _g = gB0 + (size_t)(kt2) * 64 + (size_t)(h) * 32 * ldbS;         \
    char* _l = lBc + ((bsel) << 15) + ((h) << 14) + ldsW;                       \
    gload_lds16(_g, _l);                                                        \
    gload_lds16(_g + 128 * ldbS, _l + (1 << 13));                               \
  } while (0)
#define BAR() __builtin_amdgcn_s_barrier()
#define LGKM0()                                                                \
  do {                                                                         \
    asm volatile("s_waitcnt lgkmcnt(0)" ::: "memory");                         \
    __builtin_amdgcn_sched_barrier(0);                                         \
  } while (0)
#define WAITV(N) asm volatile("s_waitcnt vmcnt(" #N ")" ::: "memory")

  f32x4 acc[8][4];
  const f32x4 z = {0.f, 0.f, 0.f, 0.f};
#pragma unroll
  for (int i = 0; i < 8; i++)
#pragma unroll
    for (int j = 0; j < 4; j++) acc[i][j] = z;

  short8 aq[4][2];      // current msub A-frags [fmL][kk]
  short8 bq[2][2][2];   // B-frags [nsub][fnL][kk]

  const int aB = (wr << 13) + (fr << 7);    // rowgroup-base(wr) + fr row
  const int bB = (wc << 12) + (fr << 7);
  const int colb0 = ((qd << 4)) ^ swzx;           // kk=0
  const int colb1 = (64 + (qd << 4)) ^ swzx;      // kk=1

  STG_A(0, 0, 0); STG_B(0, 0, 0); STG_A(1, 0, 0); STG_B(1, 0, 0);
  STG_A(0, 1, 1); STG_B(0, 1, 1); STG_A(1, 1, 1);
  WAITV(10);
  BAR();

  for (int kt = 0; kt < nkt; ++kt) {
    const int buf = kt & 1, nb = buf ^ 1;
    const int bo = buf << 15;
    // ---- P0: Q(msub0, nsub0); 12 ds_reads; stage B[kt+1]h1; wait {A,B}[kt]h1
#pragma unroll
    for (int fmL = 0; fmL < 4; fmL++) {
      aq[fmL][0] = ld8(lAc + bo + aB + (fmL << 11) + colb0);
      aq[fmL][1] = ld8(lAc + bo + aB + (fmL << 11) + colb1);
    }
#pragma unroll
    for (int fnL = 0; fnL < 2; fnL++) {
      bq[0][fnL][0] = ld8(lBc + bo + bB + (fnL << 11) + colb0);
      bq[0][fnL][1] = ld8(lBc + bo + bB + (fnL << 11) + colb1);
    }
    if (kt + 1 < nkt) { STG_B(1, nb, kt + 1); }
    if (kt == nkt - 1) { WAITV(0); } else { WAITV(8); }
    BAR(); LGKM0();
    mfma_q<0, 0>(acc, aq, bq);
    BAR();
    // ---- P1: Q(msub0, nsub1); 4 ds_reads; stage A[kt+2]h0
#pragma unroll
    for (int fnL = 0; fnL < 2; fnL++) {
      bq[1][fnL][0] = ld8(lBc + bo + bB + (1 << 14) + (fnL << 11) + colb0);
      bq[1][fnL][1] = ld8(lBc + bo + bB + (1 << 14) + (fnL << 11) + colb1);
    }
    if (kt + 2 < nkt) { STG_A(0, buf, kt + 2); }
    BAR(); LGKM0();
    mfma_q<0, 1>(acc, aq, bq);
    BAR();
    // ---- P2: Q(msub1, nsub1); 8 ds_reads (A msub1); stage B[kt+2]h0
#pragma unroll
    for (int fmL = 0; fmL < 4; fmL++) {
      aq[fmL][0] = ld8(lAc + bo + aB + (1 << 14) + (fmL << 11) + colb0);
      aq[fmL][1] = ld8(lAc + bo + aB + (1 << 14) + (fmL << 11) + colb1);
    }
    if (kt + 2 < nkt) { STG_B(0, buf, kt + 2); }
    BAR(); LGKM0();
    mfma_q<1, 1>(acc, aq, bq);
    BAR();
    // ---- P3: Q(msub1, nsub0); no ds_reads; stage A[kt+2]h1; wait {A,B}[kt+1]h0
    if (kt + 2 < nkt) { STG_A(1, buf, kt + 2); }
    if (kt < nkt - 2) { WAITV(10); }
    else if (kt == nkt - 2) { WAITV(4); }
    BAR(); LGKM0();
    mfma_q<1, 0>(acc, aq, bq);
    BAR();
  }

#undef STG_A
#undef STG_B
#undef BAR
#undef LGKM0
#undef WAITV

  const int mBase = m0 + wr * 128 + qd * 4;
  const int nBase = n0 + wc * 64 + fr;
#pragma unroll
  for (int fm = 0; fm < 8; fm++)
#pragma unroll
    for (int r = 0; r < 4; r++) {
      int mrow = mBase + fm * 16 + r;
      if (mrow < M) {
#pragma unroll
        for (int fn = 0; fn < 4; fn++)
          outB[(size_t)mrow * ldob + nBase + fn * 16] = f2bf(acc[fm][fn][r]);
      }
    }
}

// ---------------- aggregation (pull, wave per node, 4-edge unrolled) ----------------

struct AggJob {
  const u16* H;
  const int* offs; const int* csrc; const float* cw; const float* dinv;
  const float* bias;
  float* outF; u16* outB;
  long obOff; int colOff;
};

template <int CPL>
__global__ void k_agg(AggJob j0, AggJob j1, AggJob j2, int ldh, int ldf, int ldob,
                      int relu) {
  AggJob jb = j0;
  if (blockIdx.y == 1) jb = j1;
  if (blockIdx.y == 2) jb = j2;
  int wid = blockIdx.x * (blockDim.x >> 6) + (threadIdx.x >> 6);
  if (wid >= NN) return;
  int l = threadIdx.x & 63;
  const u16* hbase = jb.H + jb.colOff + (size_t)l * CPL;
  float acc[CPL], f0[CPL], f1[CPL], f2[CPL], f3[CPL];
  float dv = jb.dinv[wid];
  float sw = dv * dv;
  if (CPL == 8) ld_bf16x8(hbase + (size_t)wid * ldh, f0);
  else          ld_bf16x4(hbase + (size_t)wid * ldh, f0);
#pragma unroll
  for (int j = 0; j < CPL; j++) acc[j] = f0[j] * sw;
  int e = jb.offs[wid], e1 = jb.offs[wid + 1];
  for (; e + 4 <= e1; e += 4) {
    int s0 = jb.csrc[e], s1 = jb.csrc[e + 1], s2 = jb.csrc[e + 2], s3 = jb.csrc[e + 3];
    float w0 = jb.cw[e], w1 = jb.cw[e + 1], w2 = jb.cw[e + 2], w3 = jb.cw[e + 3];
    if (CPL == 8) {
      ld_bf16x8(hbase + (size_t)s0 * ldh, f0); ld_bf16x8(hbase + (size_t)s1 * ldh, f1);
      ld_bf16x8(hbase + (size_t)s2 * ldh, f2); ld_bf16x8(hbase + (size_t)s3 * ldh, f3);
    } else {
      ld_bf16x4(hbase + (size_t)s0 * ldh, f0); ld_bf16x4(hbase + (size_t)s1 * ldh, f1);
      ld_bf16x4(hbase + (size_t)s2 * ldh, f2); ld_bf16x4(hbase + (size_t)s3 * ldh, f3);
    }
#pragma unroll
    for (int j = 0; j < CPL; j++) acc[j] += f0[j] * w0;
#pragma unroll
    for (int j = 0; j < CPL; j++) acc[j] += f1[j] * w1;
#pragma unroll
    for (int j = 0; j < CPL; j++) acc[j] += f2[j] * w2;
#pragma unroll
    for (int j = 0; j < CPL; j++) acc[j] += f3[j] * w3;
  }
  for (; e < e1; ++e) {
    int s0 = jb.csrc[e];
    float w0 = jb.cw[e];
    if (CPL == 8) ld_bf16x8(hbase + (size_t)s0 * ldh, f0);
    else          ld_bf16x4(hbase + (size_t)s0 * ldh, f0);
#pragma unroll
    for (int j = 0; j < CPL; j++) acc[j] += f0[j] * w0;
  }
  const float* bp = jb.bias + l * CPL;
#pragma unroll
  for (int j = 0; j < CPL; j++) {
    float v = acc[j] + bp[j];
    if (relu) v = v > 0.f ? v : 0.f;
    acc[j] = v;
  }
  if (jb.outF) {
    float* q = jb.outF + (size_t)wid * ldf + l * CPL;
#pragma unroll
    for (int j = 0; j < CPL; j++) q[j] = acc[j];
  }
  if (jb.outB) {
    u16* q = jb.outB + (size_t)wid * ldob + jb.obOff + l * CPL;
#pragma unroll
    for (int j = 0; j < CPL; j++) q[j] = f2bf(acc[j]);
  }
}

// ---------------- launch ----------------

extern "C" void kernel_launch(void* const* d_in, const int* in_sizes, int n_in,
                              void* d_out, int out_size, void* d_ws, size_t ws_size,
                              hipStream_t stream) {
  (void)in_sizes; (void)n_in; (void)out_size; (void)ws_size;
  const float* x_RNA = (const float*)d_in[0];
  const float* x_ADT = (const float*)d_in[1];
  EJobs ej;
  ej.ei[0] = (const int*)d_in[2]; ej.ew[0] = (const float*)d_in[3];
  ej.ei[1] = (const int*)d_in[4]; ej.ew[1] = (const float*)d_in[5];
  ej.ei[2] = (const int*)d_in[6]; ej.ew[2] = (const float*)d_in[7];
  const float* W_rna1 = (const float*)d_in[8];  const float* b_rna1 = (const float*)d_in[9];
  const float* W_rna2 = (const float*)d_in[10]; const float* b_rna2 = (const float*)d_in[11];
  const float* W_p3   = (const float*)d_in[12]; const float* b_p3   = (const float*)d_in[13];
  const float* W_sim  = (const float*)d_in[14]; const float* b_sim  = (const float*)d_in[15];
  const float* W_dist = (const float*)d_in[16]; const float* b_dist = (const float*)d_in[17];
  const float* W_f1   = (const float*)d_in[18]; const float* b_f1   = (const float*)d_in[19];
  const float* W_f2   = (const float*)d_in[20]; const float* b_f2   = (const float*)d_in[21];
  float* out = (float*)d_out;

  char* p = (char*)d_ws;
  auto alloc = [&](size_t bytes) {
    char* r = p;
    p += (bytes + 255) & ~(size_t)255;
    return r;
  };
  u16* WcT   = (u16*)alloc((size_t)1024 * KX * 2);
  u16* WsT   = (u16*)alloc((size_t)OUTC * HID * 2);
  u16* WdT   = (u16*)alloc((size_t)OUTC * HID * 2);
  u16* Wf1T  = (u16*)alloc((size_t)OUTC * HID * 2);
  u16* Wp3T  = (u16*)alloc((size_t)OUTC * KQ * 2);
  u16* WcatT = (u16*)alloc((size_t)OUTC * 768 * 2);
  float* bias2 = (float*)alloc(OUTC * 4);
  u16* ADTb = (u16*)alloc((size_t)NN * KQ * 2);
  u16* H1   = (u16*)alloc((size_t)NN * 1024 * 2);  // later: H2s|H2d|H2p
  u16* B2   = (u16*)alloc((size_t)NN * 1024 * 2);  // XS|XD, later XSDP
  float* deg = (float*)alloc((size_t)3 * NN * 4);
  int* cnt   = (int*)alloc((size_t)3 * NN * 4);
  int* offs  = (int*)alloc((size_t)3 * (NN + 1) * 4);
  int* csrc  = (int*)alloc((size_t)3 * NE * 4);
  float* cwn = (float*)alloc((size_t)3 * NE * 4);
  int* part  = (int*)alloc(3 * 128 * 4);

  u16* Xb   = (u16*)d_out;   // bf16 x_RNA scratch: dead before first f32 output write
  u16* XS   = B2;
  u16* XD   = B2 + (size_t)NN * 512;
  u16* XSDP = B2;            // [NN, 768] = x_sim | x_dist | pro (bf16), after A2
  u16* H2s  = H1;
  u16* H2d  = H1 + (size_t)NN * 256;
  u16* H2p  = H1 + (size_t)NN * 512;

  // CSR replica state carved from B2 (dead until A1): dcR u64 | curR | subO
  u64* dcR  = (u64*)B2;                         // [NREP][3][NN] packed (cnt<<48|deg_fix)
  int* curR = (int*)(dcR + NREP * 3 * NN);
  int* subO = curR + NREP * 3 * NN;

  const int T = 256;
  // zero dcR + curR (5.76 MB) — prep's EC round accumulates atomically into dcR
  hipMemsetAsync(dcR, 0, (size_t)NREP * 3 * NN * 8 + (size_t)NREP * 3 * NN * 4, stream);

  Prep P;
  P.xR = x_RNA; P.xA = x_ADT; P.W1 = W_rna1; P.W2 = W_rna2;
  P.Ws0 = W_sim; P.Ws1 = W_dist; P.Ws2 = W_f1; P.Ws3 = W_f2; P.Ws4 = W_p3;
  P.Wo0 = WsT; P.Wo1 = WdT; P.Wo2 = Wf1T; P.Wo3 = nullptr; P.Wo4 = Wp3T;
  P.bf1 = b_f1; P.bf2 = b_f2;
  P.Xb = Xb; P.ADTb = ADTb; P.WcT = WcT; P.WcatT = WcatT; P.bias2 = bias2;
  P.ej = ej; P.dcR = dcR;
  P.Wo3 = (u16*)(cwn);  // dead scratch until k_fill_csr3; wT5 finishes in k_prep before it
  k_prep<<<26553, T, 0, stream>>>(P);

  k_scan_a<<<dim3(NB79, 3), 256, 0, stream>>>(dcR, subO, deg, cnt, part);
  k_scan_b<<<1, 128, 0, stream>>>(part);
  k_scan_c<<<dim3(NB79, 3), 256, 0, stream>>>(cnt, part, offs);
  k_fill_csr3<<<dim3((NE + T - 1) / T, 3), T, 0, stream>>>(ej, deg, offs, subO, curR, csrc, cwn);

  GemmJob jz = {};
  // G1: all 79 m-tiles x 4 n-tiles on the 8-phase kernel (grid (8,40), 316 active)
  k_gemm8<<<dim3(8, 40), 512, 0, stream>>>(Xb, WcT, H1, KX, KX, 1024, KX >> 6, NN);
  // A1: XS = relu(agg_sim(H1[:,:512]) + b_rna1); XD likewise (dist)
  AggJob a0 = {H1, offs, csrc, cwn, deg, b_rna1, nullptr, XS, 0, 0};
  AggJob a1 = {H1, offs + (NN + 1), csrc + NE, cwn + NE, deg + NN, b_rna2, nullptr, XD, 0, 512};
  k_agg<8><<<dim3(NN / 4, 2), 256, 0, stream>>>(a0, a1, a1, 1024, 0, 512, 1);
  // G2: H2s=XS@W_sim, H2d=XD@W_dist, H2p=ADTb@W_p3
  GemmJob g2a = {XS, WsT, nullptr, nullptr, H2s, HID, HID, HID};
  GemmJob g2b = {XD, WdT, nullptr, nullptr, H2d, HID, HID, HID};
  GemmJob g2c = {ADTb, Wp3T, nullptr, nullptr, H2p, KQ, KQ, KQ};
  k_gemm<3><<<dim3(2, 157, 3), 256, 0, stream>>>(g2a, g2b, g2c, NN, 0, 256, 0, 0);
  // A2: x_sim, x_dist, pro -> f32 outputs + bf16 into XSDP
  AggJob b0 = {H2s, offs, csrc, cwn, deg, b_sim, out, XSDP, 0, 0};
  AggJob b1 = {H2d, offs + (NN + 1), csrc + NE, cwn + NE, deg + NN, b_dist,
               out + OUTSZ, XSDP, 256, 0};
  AggJob b2 = {H2p, offs + 2 * (NN + 1), csrc + 2 * NE, cwn + 2 * NE, deg + 2 * NN, b_p3,
               out + 4 * OUTSZ, XSDP, 512, 0};
  k_agg<4><<<dim3(NN / 4, 3), 256, 0, stream>>>(b0, b1, b2, 256, 256, 768, 0);
  // G5 (2 jobs): fused = XSDP[:,:512]@W_f1 + b_f1 ; fused_pro = XSDP@Wcat + bias2
  GemmJob g5a = {XSDP, Wf1T, b_f1, out + 2 * OUTSZ, nullptr, 768, 512, 512};
  GemmJob g5b = {XSDP, WcatT, bias2, out + 3 * OUTSZ, nullptr, 768, 768, 768};
  k_gemm<2><<<dim3(2, 157, 2), 256, 0, stream>>>(g5a, g5b, jz, NN, 256, 0, 0, 0);
}